// Round 1
// baseline (1212.571 us; speedup 1.0000x reference)
//
#include <hip/hip_runtime.h>
#include <math.h>

#define N_NODES 20000
#define N_EDGES 256000
#define ETOT (N_EDGES + N_NODES)

// ---------------------------------------------------------------------------
// Edge preprocessing: counting sort by dst, deterministic order within segment
// ---------------------------------------------------------------------------

__global__ void hist_kernel(const int* __restrict__ ei, int* __restrict__ cnt) {
    for (int e = blockIdx.x * blockDim.x + threadIdx.x; e < ETOT;
         e += gridDim.x * blockDim.x) {
        int d = (e < N_EDGES) ? ei[N_EDGES + e] : (e - N_EDGES);
        atomicAdd(&cnt[d], 1);
    }
}

__global__ __launch_bounds__(1024) void scan_kernel(int* __restrict__ cursor,
                                                    int* __restrict__ row_start) {
    __shared__ int sh[1024];
    __shared__ int base_sh;
    int tid = threadIdx.x;
    if (tid == 0) { base_sh = 0; row_start[0] = 0; }
    __syncthreads();
    for (int c0 = 0; c0 < N_NODES; c0 += 1024) {
        int i = c0 + tid;
        int v = (i < N_NODES) ? cursor[i] : 0;
        sh[tid] = v;
        __syncthreads();
        for (int off = 1; off < 1024; off <<= 1) {
            int t2 = (tid >= off) ? sh[tid - off] : 0;
            __syncthreads();
            sh[tid] += t2;
            __syncthreads();
        }
        int incl = sh[tid];
        int base = base_sh;
        __syncthreads();  // everyone reads base before it is updated
        if (i < N_NODES) {
            row_start[i + 1] = base + incl;
            cursor[i] = base + incl - v;  // exclusive start (scatter cursor)
        }
        if (tid == 1023) base_sh = base + sh[1023];
        __syncthreads();
    }
}

__global__ void scatter_kernel(const int* __restrict__ ei, int* __restrict__ cursor,
                               int* __restrict__ sorted_id) {
    for (int e = blockIdx.x * blockDim.x + threadIdx.x; e < ETOT;
         e += gridDim.x * blockDim.x) {
        int d = (e < N_EDGES) ? ei[N_EDGES + e] : (e - N_EDGES);
        int pos = atomicAdd(&cursor[d], 1);
        sorted_id[pos] = e;
    }
}

// Deterministic order: insertion-sort each node's segment by edge id, then
// materialize the source index array.
__global__ void segsort_kernel(const int* __restrict__ ei,
                               const int* __restrict__ row_start,
                               int* __restrict__ sorted_id,
                               int* __restrict__ sorted_src) {
    int n = blockIdx.x * blockDim.x + threadIdx.x;
    if (n >= N_NODES) return;
    int s = row_start[n], e = row_start[n + 1];
    for (int i = s + 1; i < e; i++) {
        int v = sorted_id[i];
        int j = i - 1;
        while (j >= s && sorted_id[j] > v) { sorted_id[j + 1] = sorted_id[j]; j--; }
        sorted_id[j + 1] = v;
    }
    for (int i = s; i < e; i++) {
        int id = sorted_id[i];
        sorted_src[i] = (id < N_EDGES) ? ei[id] : (id - N_EDGES);
    }
}

// ---------------------------------------------------------------------------
// fp32 GEMM: C[r,c] = sum_k A[r,k]*B[c,k] (+bias[c]).  A:[R,K] B:[Cout,K]
// 64x64 tile, BK=16, 256 threads, 4x4 microtile.
// ---------------------------------------------------------------------------
__global__ __launch_bounds__(256) void gemm_tn(const float* __restrict__ A,
                                               const float* __restrict__ B,
                                               const float* __restrict__ bias,
                                               float* __restrict__ C,
                                               int R, int K, int Cout) {
    __shared__ float As[16][68];
    __shared__ float Bs[16][68];
    int tid = threadIdx.x;
    int br = blockIdx.x * 64;
    int bc = blockIdx.y * 64;
    int tr = tid >> 4;          // 0..15
    int tc = tid & 15;          // 0..15
    int lr = tid >> 2;          // 0..63
    int lk = (tid & 3) << 2;    // 0,4,8,12
    float acc[4][4] = {};
    for (int k0 = 0; k0 < K; k0 += 16) {
        int r = br + lr;
        float4 va = make_float4(0.f, 0.f, 0.f, 0.f);
        if (r < R) va = *reinterpret_cast<const float4*>(A + (size_t)r * K + k0 + lk);
        float4 vb = *reinterpret_cast<const float4*>(B + (size_t)(bc + lr) * K + k0 + lk);
        As[lk + 0][lr] = va.x; As[lk + 1][lr] = va.y;
        As[lk + 2][lr] = va.z; As[lk + 3][lr] = va.w;
        Bs[lk + 0][lr] = vb.x; Bs[lk + 1][lr] = vb.y;
        Bs[lk + 2][lr] = vb.z; Bs[lk + 3][lr] = vb.w;
        __syncthreads();
#pragma unroll
        for (int k = 0; k < 16; ++k) {
            float a[4], b[4];
#pragma unroll
            for (int i = 0; i < 4; i++) a[i] = As[k][tr * 4 + i];
#pragma unroll
            for (int j = 0; j < 4; j++) b[j] = Bs[k][tc * 4 + j];
#pragma unroll
            for (int i = 0; i < 4; i++)
#pragma unroll
                for (int j = 0; j < 4; j++)
                    acc[i][j] = fmaf(a[i], b[j], acc[i][j]);
        }
        __syncthreads();
    }
#pragma unroll
    for (int i = 0; i < 4; i++) {
        int r = br + tr * 4 + i;
        if (r < R) {
#pragma unroll
            for (int j = 0; j < 4; j++) {
                int c = bc + tc * 4 + j;
                float v = acc[i][j];
                if (bias) v += bias[c];
                C[(size_t)r * Cout + c] = v;
            }
        }
    }
}

// ---------------------------------------------------------------------------
// Attention coefficients: al_s[n,h] = dot(xp[n,h*128:(h+1)*128], a_src[h]),
// same for al_d.  One wave per node.
// ---------------------------------------------------------------------------
template <int HEADS>
__global__ void attn_coef(const float* __restrict__ xp, const float* __restrict__ a_s,
                          const float* __restrict__ a_d, float* __restrict__ al_s,
                          float* __restrict__ al_d) {
    int wave = (blockIdx.x * blockDim.x + threadIdx.x) >> 6;
    int lane = threadIdx.x & 63;
    if (wave >= N_NODES) return;
    const int C = HEADS * 128;
    float accs[HEADS] = {}, accd[HEADS] = {};
#pragma unroll
    for (int j = 0; j < C / 64; j++) {
        int c = lane + 64 * j;
        int h = j >> 1;  // c>>7, independent of lane
        float v = xp[(size_t)wave * C + c];
        accs[h] = fmaf(v, a_s[c], accs[h]);
        accd[h] = fmaf(v, a_d[c], accd[h]);
    }
#pragma unroll
    for (int h = 0; h < HEADS; h++) {
        float s = accs[h], d = accd[h];
#pragma unroll
        for (int off = 32; off; off >>= 1) {
            s += __shfl_down(s, off);
            d += __shfl_down(d, off);
        }
        if (lane == 0) {
            al_s[wave * HEADS + h] = s;
            al_d[wave * HEADS + h] = d;
        }
    }
}

// ---------------------------------------------------------------------------
// Fused GAT aggregation + bias + ELU + LayerNorm + residual.
// One block per node.  C = heads*128 channels, block = C/2 threads.
// RES: 0 none, 1 add h_res[n, 0:C], 2 add pooled (h_res width 4C -> C).
// ---------------------------------------------------------------------------
template <int C, int HEADS, int RES>
__global__ __launch_bounds__(C / 2) void gat_aggregate(
    const float* __restrict__ xp, const float* __restrict__ al_s,
    const float* __restrict__ al_d, const int* __restrict__ row_start,
    const int* __restrict__ srcs, const float* __restrict__ bias,
    const float* __restrict__ gamma, const float* __restrict__ beta,
    const float* __restrict__ h_res, float* __restrict__ out,
    float* __restrict__ out2, int out2_stride) {
    const int BLK = C / 2;
    const int NW = BLK / 64;
    int n = blockIdx.x;
    int tid = threadIdx.x;
    int lane = tid & 63, wv = tid >> 6;
    __shared__ float m_sh[HEADS], s_sh[HEADS];
    __shared__ int src_sh[64];
    __shared__ float w_sh[64 * HEADS];
    __shared__ float red_sh[2 * NW];
    int base = row_start[n];
    int deg = row_start[n + 1] - base;

    // ---- segment softmax stats (max then sum) ----
    for (int h = wv; h < HEADS; h += NW) {
        float ald = al_d[n * HEADS + h];
        float m = -3.4e38f;
        for (int e = lane; e < deg; e += 64) {
            float v = al_s[srcs[base + e] * HEADS + h] + ald;
            v = v > 0.f ? v : 0.2f * v;
            m = fmaxf(m, v);
        }
#pragma unroll
        for (int off = 32; off; off >>= 1) m = fmaxf(m, __shfl_xor(m, off));
        float s = 0.f;
        for (int e = lane; e < deg; e += 64) {
            float v = al_s[srcs[base + e] * HEADS + h] + ald;
            v = v > 0.f ? v : 0.2f * v;
            s += expf(v - m);
        }
#pragma unroll
        for (int off = 32; off; off >>= 1) s += __shfl_xor(s, off);
        if (lane == 0) { m_sh[h] = m; s_sh[h] = s + 1e-16f; }
    }
    __syncthreads();

    // ---- weighted message accumulation, chunks of 64 edges ----
    float acc0 = 0.f, acc1 = 0.f;
    int c0 = tid, c1 = tid + BLK;
    int h0 = c0 >> 7, h1 = c1 >> 7;
    for (int cb = 0; cb < deg; cb += 64) {
        int clen = min(64, deg - cb);
        if (tid < clen) src_sh[tid] = srcs[base + cb + tid];
        __syncthreads();
        if (tid < clen * HEADS) {
            int e = tid / HEADS, h = tid % HEADS;
            int sidx = src_sh[e];
            float v = al_s[sidx * HEADS + h] + al_d[n * HEADS + h];
            v = v > 0.f ? v : 0.2f * v;
            w_sh[tid] = expf(v - m_sh[h]) / s_sh[h];
        }
        __syncthreads();
        for (int j = 0; j < clen; j++) {
            const float* row = &xp[(size_t)src_sh[j] * C];
            acc0 = fmaf(w_sh[j * HEADS + h0], row[c0], acc0);
            acc1 = fmaf(w_sh[j * HEADS + h1], row[c1], acc1);
        }
        __syncthreads();
    }

    // ---- epilogue: +bias, ELU, LayerNorm, residual ----
    float v0 = acc0 + bias[c0];
    float v1 = acc1 + bias[c1];
    v0 = v0 > 0.f ? v0 : expm1f(v0);
    v1 = v1 > 0.f ? v1 : expm1f(v1);
    float s = v0 + v1, q = v0 * v0 + v1 * v1;
#pragma unroll
    for (int off = 32; off; off >>= 1) {
        s += __shfl_xor(s, off);
        q += __shfl_xor(q, off);
    }
    if (NW > 1) {
        if (lane == 0) { red_sh[wv * 2] = s; red_sh[wv * 2 + 1] = q; }
        __syncthreads();
        s = 0.f; q = 0.f;
#pragma unroll
        for (int w = 0; w < NW; w++) { s += red_sh[w * 2]; q += red_sh[w * 2 + 1]; }
    }
    float mu = s / C;
    float var = q / C - mu * mu;
    float rstd = 1.0f / sqrtf(var + 1e-5f);
    v0 = (v0 - mu) * rstd * gamma[c0] + beta[c0];
    v1 = (v1 - mu) * rstd * gamma[c1] + beta[c1];
    if (RES == 1) {
        v0 += h_res[(size_t)n * C + c0];
        v1 += h_res[(size_t)n * C + c1];
    } else if (RES == 2) {
        const float* r = &h_res[(size_t)n * C * 4];
        v0 += 0.25f * (r[4 * c0] + r[4 * c0 + 1] + r[4 * c0 + 2] + r[4 * c0 + 3]);
        v1 += 0.25f * (r[4 * c1] + r[4 * c1 + 1] + r[4 * c1 + 2] + r[4 * c1 + 3]);
    }
    out[(size_t)n * C + c0] = v0;
    out[(size_t)n * C + c1] = v1;
    if (out2) {
        out2[(size_t)n * out2_stride + c0] = v0;
        out2[(size_t)n * out2_stride + c1] = v1;
    }
}

// ---------------------------------------------------------------------------
// Temporal self-attention over T=2 states. qkv:[N*2, 384] -> om:[N,128]
// om = mean over t of attention output (out proj applied afterwards via GEMM).
// ---------------------------------------------------------------------------
__global__ __launch_bounds__(128) void temporal_attn(const float* __restrict__ qkv,
                                                     float* __restrict__ om) {
    __shared__ float sh[768];
    int n = blockIdx.x;
    int c = threadIdx.x;  // 0..127
    for (int i = c; i < 768; i += 128) {
        int t = i / 384;
        sh[i] = qkv[(size_t)(n * 2 + t) * 384 + (i - t * 384)];
    }
    __syncthreads();
    int head = c >> 5;
    int hb = head * 32;
    const float scale = 0.17677669529663687f;  // 1/sqrt(32)
    float o[2];
#pragma unroll
    for (int qt = 0; qt < 2; qt++) {
        float s0 = 0.f, s1 = 0.f;
#pragma unroll
        for (int d = 0; d < 32; d++) {
            float qv = sh[qt * 384 + hb + d];
            s0 = fmaf(qv, sh[0 * 384 + 128 + hb + d], s0);
            s1 = fmaf(qv, sh[1 * 384 + 128 + hb + d], s1);
        }
        s0 *= scale; s1 *= scale;
        float m = fmaxf(s0, s1);
        float p0 = expf(s0 - m), p1 = expf(s1 - m);
        float inv = 1.0f / (p0 + p1);
        o[qt] = p0 * inv * sh[0 * 384 + 256 + c] + p1 * inv * sh[1 * 384 + 256 + c];
    }
    om[(size_t)n * 128 + c] = 0.5f * (o[0] + o[1]);
}

// ---------------------------------------------------------------------------

extern "C" void kernel_launch(void* const* d_in, const int* in_sizes, int n_in,
                              void* d_out, int out_size, void* d_ws, size_t ws_size,
                              hipStream_t stream) {
    const float* x   = (const float*)d_in[0];
    const int*   ei  = (const int*)d_in[1];
    const float* Wp  = (const float*)d_in[2];
    const float* bp  = (const float*)d_in[3];
    const float* W0  = (const float*)d_in[4];
    const float* as0 = (const float*)d_in[5];
    const float* ad0 = (const float*)d_in[6];
    const float* b0  = (const float*)d_in[7];
    const float* W1  = (const float*)d_in[8];
    const float* as1 = (const float*)d_in[9];
    const float* ad1 = (const float*)d_in[10];
    const float* b1  = (const float*)d_in[11];
    const float* W2  = (const float*)d_in[12];
    const float* as2 = (const float*)d_in[13];
    const float* ad2 = (const float*)d_in[14];
    const float* b2  = (const float*)d_in[15];
    const float* g0  = (const float*)d_in[16];
    const float* be0 = (const float*)d_in[17];
    const float* g1  = (const float*)d_in[18];
    const float* be1 = (const float*)d_in[19];
    const float* g2  = (const float*)d_in[20];
    const float* be2 = (const float*)d_in[21];
    const float* Wqkv = (const float*)d_in[22];
    const float* bqkv = (const float*)d_in[23];
    const float* Wo  = (const float*)d_in[24];
    const float* bo  = (const float*)d_in[25];
    float* out = (float*)d_out;

    const int N = N_NODES;
    // workspace layout
    float* f = (float*)d_ws;
    const size_t NH = (size_t)N * 512;
    float* hA     = f;
    float* hB     = hA + NH;
    float* xp     = hB + NH;
    float* states = xp + NH;                        // N*256
    float* als    = states + (size_t)N * 256;       // N*4
    float* ald    = als + (size_t)N * 4;            // N*4
    int* row_start  = (int*)(ald + (size_t)N * 4);  // N+1
    int* cursor     = row_start + (N + 1);          // N
    int* sorted_id  = cursor + N;                   // ETOT
    int* sorted_src = sorted_id + ETOT;             // ETOT
    float* qkv = hA;  // reuse after GAT layers (needs N*768 <= N*1024)
    float* om  = xp;  // reuse

    // ---- edge preprocessing (deterministic counting sort by dst) ----
    hipMemsetAsync(cursor, 0, N * sizeof(int), stream);
    hist_kernel<<<1024, 256, 0, stream>>>(ei, cursor);
    scan_kernel<<<1, 1024, 0, stream>>>(cursor, row_start);
    scatter_kernel<<<1024, 256, 0, stream>>>(ei, cursor, sorted_id);
    segsort_kernel<<<(N + 255) / 256, 256, 0, stream>>>(ei, row_start, sorted_id,
                                                        sorted_src);

    // ---- input projection: h = x @ Wp.T + bp  [N,128] ----
    {
        dim3 g((N + 63) / 64, 128 / 64);
        gemm_tn<<<g, 256, 0, stream>>>(x, Wp, bp, hA, N, 128, 128);
    }

    float* cur = hA;
    float* nxt = hB;
    for (int t = 0; t < 2; t++) {
        // ----- layer 0: in 128 -> out 512 (4 heads, concat) -----
        {
            dim3 g((N + 63) / 64, 512 / 64);
            gemm_tn<<<g, 256, 0, stream>>>(cur, W0, nullptr, xp, N, 128, 512);
            attn_coef<4><<<(N * 64 + 255) / 256, 256, 0, stream>>>(xp, as0, ad0, als, ald);
            gat_aggregate<512, 4, 0><<<N, 256, 0, stream>>>(
                xp, als, ald, row_start, sorted_src, b0, g0, be0, nullptr, nxt,
                nullptr, 0);
            float* tmp = cur; cur = nxt; nxt = tmp;
        }
        // ----- layer 1: in 512 -> out 512 (4 heads, concat), residual add -----
        {
            dim3 g((N + 63) / 64, 512 / 64);
            gemm_tn<<<g, 256, 0, stream>>>(cur, W1, nullptr, xp, N, 512, 512);
            attn_coef<4><<<(N * 64 + 255) / 256, 256, 0, stream>>>(xp, as1, ad1, als, ald);
            gat_aggregate<512, 4, 1><<<N, 256, 0, stream>>>(
                xp, als, ald, row_start, sorted_src, b1, g1, be1, cur, nxt,
                nullptr, 0);
            float* tmp = cur; cur = nxt; nxt = tmp;
        }
        // ----- layer 2: in 512 -> out 128 (1 head), pooled residual -----
        {
            dim3 g((N + 63) / 64, 128 / 64);
            gemm_tn<<<g, 256, 0, stream>>>(cur, W2, nullptr, xp, N, 512, 128);
            attn_coef<1><<<(N * 64 + 255) / 256, 256, 0, stream>>>(xp, as2, ad2, als, ald);
            gat_aggregate<128, 1, 2><<<N, 64, 0, stream>>>(
                xp, als, ald, row_start, sorted_src, b2, g2, be2, cur, nxt,
                states + (size_t)t * 128, 256);
            float* tmp = cur; cur = nxt; nxt = tmp;
        }
    }

    // ---- temporal attention ----
    {
        dim3 g((2 * N + 63) / 64, 384 / 64);
        gemm_tn<<<g, 256, 0, stream>>>(states, Wqkv, bqkv, qkv, 2 * N, 128, 384);
    }
    temporal_attn<<<N, 128, 0, stream>>>(qkv, om);
    {
        dim3 g((N + 63) / 64, 128 / 64);
        gemm_tn<<<g, 256, 0, stream>>>(om, Wo, bo, out, N, 128, 128);
    }
}

// Round 5
// 907.951 us; speedup vs baseline: 1.3355x; 1.3355x over previous
//
#include <hip/hip_runtime.h>
#include <math.h>

#define N_NODES 20000
#define N_EDGES 256000
#define ETOT (N_EDGES + N_NODES)
#define NPAD 20096    // 157*128
#define NPAD2 40064   // 313*128 (2N rows padded)

typedef __attribute__((ext_vector_type(8))) short bf16x8;
typedef __attribute__((ext_vector_type(4))) float f32x4;

__device__ __forceinline__ unsigned short f2bf(float f) {
    unsigned int u = __builtin_bit_cast(unsigned int, f);
    u = (u + 0x7fff + ((u >> 16) & 1)) >> 16;
    return (unsigned short)u;
}

__device__ __forceinline__ void gload_lds16(const void* g, void* l) {
    __builtin_amdgcn_global_load_lds(
        (const __attribute__((address_space(1))) void*)g,
        (__attribute__((address_space(3))) void*)l, 16, 0, 0);
}

// ---------------------------------------------------------------------------
// Edge preprocessing: counting sort by dst, deterministic order within segment
// ---------------------------------------------------------------------------

__global__ void hist_kernel(const int* __restrict__ ei, int* __restrict__ cnt) {
    for (int e = blockIdx.x * blockDim.x + threadIdx.x; e < ETOT;
         e += gridDim.x * blockDim.x) {
        int d = (e < N_EDGES) ? ei[N_EDGES + e] : (e - N_EDGES);
        atomicAdd(&cnt[d], 1);
    }
}

__global__ __launch_bounds__(1024) void scan_kernel(int* __restrict__ cursor,
                                                    int* __restrict__ row_start) {
    __shared__ int sh[1024];
    __shared__ int base_sh;
    int tid = threadIdx.x;
    if (tid == 0) { base_sh = 0; row_start[0] = 0; }
    __syncthreads();
    for (int c0 = 0; c0 < N_NODES; c0 += 1024) {
        int i = c0 + tid;
        int v = (i < N_NODES) ? cursor[i] : 0;
        sh[tid] = v;
        __syncthreads();
        for (int off = 1; off < 1024; off <<= 1) {
            int t2 = (tid >= off) ? sh[tid - off] : 0;
            __syncthreads();
            sh[tid] += t2;
            __syncthreads();
        }
        int incl = sh[tid];
        int base = base_sh;
        __syncthreads();
        if (i < N_NODES) {
            row_start[i + 1] = base + incl;
            cursor[i] = base + incl - v;
        }
        if (tid == 1023) base_sh = base + sh[1023];
        __syncthreads();
    }
}

__global__ void scatter_kernel(const int* __restrict__ ei, int* __restrict__ cursor,
                               int* __restrict__ sorted_id) {
    for (int e = blockIdx.x * blockDim.x + threadIdx.x; e < ETOT;
         e += gridDim.x * blockDim.x) {
        int d = (e < N_EDGES) ? ei[N_EDGES + e] : (e - N_EDGES);
        int pos = atomicAdd(&cursor[d], 1);
        sorted_id[pos] = e;
    }
}

__global__ void segsort_kernel(const int* __restrict__ ei,
                               const int* __restrict__ row_start,
                               int* __restrict__ sorted_id,
                               int* __restrict__ sorted_src) {
    int n = blockIdx.x * blockDim.x + threadIdx.x;
    if (n >= N_NODES) return;
    int s = row_start[n], e = row_start[n + 1];
    for (int i = s + 1; i < e; i++) {
        int v = sorted_id[i];
        int j = i - 1;
        while (j >= s && sorted_id[j] > v) { sorted_id[j + 1] = sorted_id[j]; j--; }
        sorted_id[j + 1] = v;
    }
    for (int i = s; i < e; i++) {
        int id = sorted_id[i];
        sorted_src[i] = (id < N_EDGES) ? ei[id] : (id - N_EDGES);
    }
}

// ---------------------------------------------------------------------------
// bf16 conversion
// ---------------------------------------------------------------------------
__global__ void conv_bf16(const float* __restrict__ src,
                          unsigned short* __restrict__ dst, int n) {
    int i = blockIdx.x * blockDim.x + threadIdx.x;
    if (i < n) dst[i] = f2bf(src[i]);
}

// ---------------------------------------------------------------------------
// bf16 MFMA GEMM:  C[r,c] = sum_k A[r,k]*B[c,k] (+bias[c])
// A:[R_pad,K] bf16, B:[C,K] bf16.  128x128 tile, BK=64, 256 thr (4 waves,
// each 64x64 via 4x4 x mfma_f32_16x16x32_bf16).  Row-guarded stores; loads
// rely on A padded to a 128-row multiple (pad rows zeroed).
// ---------------------------------------------------------------------------
__global__ __launch_bounds__(256) void gemm_mfma(
    const unsigned short* __restrict__ A, const unsigned short* __restrict__ B,
    const float* __restrict__ bias, float* __restrict__ Cf,
    unsigned short* __restrict__ C16, int R, int K, int ldc) {
    __shared__ unsigned short Al[128 * 64];
    __shared__ unsigned short Bl[128 * 64];
    int tid = threadIdx.x;
    int lane = tid & 63, wv = tid >> 6;
    int wr = (wv >> 1) * 64, wc = (wv & 1) * 64;
    size_t br = (size_t)blockIdx.x * 128;
    size_t bc = (size_t)blockIdx.y * 128;
    f32x4 acc[4][4] = {};
    for (int k0 = 0; k0 < K; k0 += 64) {
#pragma unroll
        for (int i = 0; i < 4; i++) {
            int idx = i * 256 + tid;
            int row = idx >> 3;
            int kb = (idx & 7) << 4;  // byte offset within the 128B row-chunk
            gload_lds16((const char*)(A + (br + row) * K + k0) + kb,
                        (char*)Al + idx * 16);
            gload_lds16((const char*)(B + (bc + row) * K + k0) + kb,
                        (char*)Bl + idx * 16);
        }
        __syncthreads();
#pragma unroll
        for (int kk = 0; kk < 2; kk++) {
            bf16x8 af[4], bfr[4];
#pragma unroll
            for (int m = 0; m < 4; m++)
                af[m] = *(const bf16x8*)&Al[(wr + m * 16 + (lane & 15)) * 64 +
                                            kk * 32 + (lane >> 4) * 8];
#pragma unroll
            for (int n = 0; n < 4; n++)
                bfr[n] = *(const bf16x8*)&Bl[(wc + n * 16 + (lane & 15)) * 64 +
                                             kk * 32 + (lane >> 4) * 8];
#pragma unroll
            for (int m = 0; m < 4; m++)
#pragma unroll
                for (int n = 0; n < 4; n++)
                    acc[m][n] = __builtin_amdgcn_mfma_f32_16x16x32_bf16(
                        af[m], bfr[n], acc[m][n], 0, 0, 0);
        }
        __syncthreads();
    }
#pragma unroll
    for (int m = 0; m < 4; m++) {
        int r0 = wr + m * 16 + (lane >> 4) * 4;
#pragma unroll
        for (int n = 0; n < 4; n++) {
            int c = (int)bc + wc + n * 16 + (lane & 15);
            float bv = bias ? bias[c] : 0.f;
#pragma unroll
            for (int j = 0; j < 4; j++) {
                size_t r = br + r0 + j;
                if (r < (size_t)R) {
                    float v = acc[m][n][j] + bv;
                    if (Cf) Cf[r * ldc + c] = v;
                    if (C16) C16[r * ldc + c] = f2bf(v);
                }
            }
        }
    }
}

// ---------------------------------------------------------------------------
// Attention coefficients (one wave per node)
// ---------------------------------------------------------------------------
template <int HEADS>
__global__ void attn_coef(const float* __restrict__ xp, const float* __restrict__ a_s,
                          const float* __restrict__ a_d, float* __restrict__ al_s,
                          float* __restrict__ al_d) {
    int wave = (blockIdx.x * blockDim.x + threadIdx.x) >> 6;
    int lane = threadIdx.x & 63;
    if (wave >= N_NODES) return;
    const int C = HEADS * 128;
    float accs[HEADS] = {}, accd[HEADS] = {};
#pragma unroll
    for (int j = 0; j < C / 64; j++) {
        int c = lane + 64 * j;
        int h = j >> 1;
        float v = xp[(size_t)wave * C + c];
        accs[h] = fmaf(v, a_s[c], accs[h]);
        accd[h] = fmaf(v, a_d[c], accd[h]);
    }
#pragma unroll
    for (int h = 0; h < HEADS; h++) {
        float s = accs[h], d = accd[h];
#pragma unroll
        for (int off = 32; off; off >>= 1) {
            s += __shfl_down(s, off);
            d += __shfl_down(d, off);
        }
        if (lane == 0) {
            al_s[wave * HEADS + h] = s;
            al_d[wave * HEADS + h] = d;
        }
    }
}

// ---------------------------------------------------------------------------
// Fused GAT aggregation + bias + ELU + LayerNorm + residual (+bf16 mirrors)
// ---------------------------------------------------------------------------
template <int C, int HEADS, int RES>
__global__ __launch_bounds__(C / 2) void gat_aggregate(
    const float* __restrict__ xp, const float* __restrict__ al_s,
    const float* __restrict__ al_d, const int* __restrict__ row_start,
    const int* __restrict__ srcs, const float* __restrict__ bias,
    const float* __restrict__ gamma, const float* __restrict__ beta,
    const float* __restrict__ h_res, float* __restrict__ out,
    unsigned short* __restrict__ out16, unsigned short* __restrict__ out2_16,
    int out2_stride) {
    const int BLK = C / 2;
    const int NW = BLK / 64;
    int n = blockIdx.x;
    int tid = threadIdx.x;
    int lane = tid & 63, wv = tid >> 6;
    __shared__ float m_sh[HEADS], s_sh[HEADS];
    __shared__ int src_sh[64];
    __shared__ float w_sh[64 * HEADS];
    __shared__ float red_sh[2 * NW];
    int base = row_start[n];
    int deg = row_start[n + 1] - base;

    for (int h = wv; h < HEADS; h += NW) {
        float ald = al_d[n * HEADS + h];
        float m = -3.4e38f;
        for (int e = lane; e < deg; e += 64) {
            float v = al_s[srcs[base + e] * HEADS + h] + ald;
            v = v > 0.f ? v : 0.2f * v;
            m = fmaxf(m, v);
        }
#pragma unroll
        for (int off = 32; off; off >>= 1) m = fmaxf(m, __shfl_xor(m, off));
        float s = 0.f;
        for (int e = lane; e < deg; e += 64) {
            float v = al_s[srcs[base + e] * HEADS + h] + ald;
            v = v > 0.f ? v : 0.2f * v;
            s += expf(v - m);
        }
#pragma unroll
        for (int off = 32; off; off >>= 1) s += __shfl_xor(s, off);
        if (lane == 0) { m_sh[h] = m; s_sh[h] = s + 1e-16f; }
    }
    __syncthreads();

    float acc0 = 0.f, acc1 = 0.f;
    int c0 = tid, c1 = tid + BLK;
    int h0 = c0 >> 7, h1 = c1 >> 7;
    for (int cb = 0; cb < deg; cb += 64) {
        int clen = min(64, deg - cb);
        if (tid < clen) src_sh[tid] = srcs[base + cb + tid];
        __syncthreads();
        if (tid < clen * HEADS) {
            int e = tid / HEADS, h = tid % HEADS;
            int sidx = src_sh[e];
            float v = al_s[sidx * HEADS + h] + al_d[n * HEADS + h];
            v = v > 0.f ? v : 0.2f * v;
            w_sh[tid] = expf(v - m_sh[h]) / s_sh[h];
        }
        __syncthreads();
        for (int j = 0; j < clen; j++) {
            const float* row = &xp[(size_t)src_sh[j] * C];
            acc0 = fmaf(w_sh[j * HEADS + h0], row[c0], acc0);
            acc1 = fmaf(w_sh[j * HEADS + h1], row[c1], acc1);
        }
        __syncthreads();
    }

    float v0 = acc0 + bias[c0];
    float v1 = acc1 + bias[c1];
    v0 = v0 > 0.f ? v0 : expm1f(v0);
    v1 = v1 > 0.f ? v1 : expm1f(v1);
    float s = v0 + v1, q = v0 * v0 + v1 * v1;
#pragma unroll
    for (int off = 32; off; off >>= 1) {
        s += __shfl_xor(s, off);
        q += __shfl_xor(q, off);
    }
    if (NW > 1) {
        if (lane == 0) { red_sh[wv * 2] = s; red_sh[wv * 2 + 1] = q; }
        __syncthreads();
        s = 0.f; q = 0.f;
#pragma unroll
        for (int w = 0; w < NW; w++) { s += red_sh[w * 2]; q += red_sh[w * 2 + 1]; }
    }
    float mu = s / C;
    float var = q / C - mu * mu;
    float rstd = 1.0f / sqrtf(var + 1e-5f);
    v0 = (v0 - mu) * rstd * gamma[c0] + beta[c0];
    v1 = (v1 - mu) * rstd * gamma[c1] + beta[c1];
    if (RES == 1) {
        v0 += h_res[(size_t)n * C + c0];
        v1 += h_res[(size_t)n * C + c1];
    } else if (RES == 2) {
        const float* r = &h_res[(size_t)n * C * 4];
        v0 += 0.25f * (r[4 * c0] + r[4 * c0 + 1] + r[4 * c0 + 2] + r[4 * c0 + 3]);
        v1 += 0.25f * (r[4 * c1] + r[4 * c1 + 1] + r[4 * c1 + 2] + r[4 * c1 + 3]);
    }
    out[(size_t)n * C + c0] = v0;
    out[(size_t)n * C + c1] = v1;
    if (out16) {
        out16[(size_t)n * C + c0] = f2bf(v0);
        out16[(size_t)n * C + c1] = f2bf(v1);
    }
    if (out2_16) {
        out2_16[(size_t)n * out2_stride + c0] = f2bf(v0);
        out2_16[(size_t)n * out2_stride + c1] = f2bf(v1);
    }
}

// ---------------------------------------------------------------------------
// Temporal self-attention over T=2 states. qkv:[2N,384] fp32 -> om16:[N,128] bf16
// ---------------------------------------------------------------------------
__global__ __launch_bounds__(128) void temporal_attn(const float* __restrict__ qkv,
                                                     unsigned short* __restrict__ om16) {
    __shared__ float sh[768];
    int n = blockIdx.x;
    int c = threadIdx.x;
    for (int i = c; i < 768; i += 128) {
        int t = i / 384;
        sh[i] = qkv[(size_t)(n * 2 + t) * 384 + (i - t * 384)];
    }
    __syncthreads();
    int head = c >> 5;
    int hb = head * 32;
    const float scale = 0.17677669529663687f;
    float o[2];
#pragma unroll
    for (int qt = 0; qt < 2; qt++) {
        float s0 = 0.f, s1 = 0.f;
#pragma unroll
        for (int d = 0; d < 32; d++) {
            float qv = sh[qt * 384 + hb + d];
            s0 = fmaf(qv, sh[0 * 384 + 128 + hb + d], s0);
            s1 = fmaf(qv, sh[1 * 384 + 128 + hb + d], s1);
        }
        s0 *= scale; s1 *= scale;
        float m = fmaxf(s0, s1);
        float p0 = expf(s0 - m), p1 = expf(s1 - m);
        float inv = 1.0f / (p0 + p1);
        o[qt] = p0 * inv * sh[0 * 384 + 256 + c] + p1 * inv * sh[1 * 384 + 256 + c];
    }
    om16[(size_t)n * 128 + c] = f2bf(0.5f * (o[0] + o[1]));
}

// ---------------------------------------------------------------------------

extern "C" void kernel_launch(void* const* d_in, const int* in_sizes, int n_in,
                              void* d_out, int out_size, void* d_ws, size_t ws_size,
                              hipStream_t stream) {
    const float* x   = (const float*)d_in[0];
    const int*   ei  = (const int*)d_in[1];
    const float* Wp  = (const float*)d_in[2];
    const float* bp  = (const float*)d_in[3];
    const float* W0  = (const float*)d_in[4];
    const float* as0 = (const float*)d_in[5];
    const float* ad0 = (const float*)d_in[6];
    const float* b0  = (const float*)d_in[7];
    const float* W1  = (const float*)d_in[8];
    const float* as1 = (const float*)d_in[9];
    const float* ad1 = (const float*)d_in[10];
    const float* b1  = (const float*)d_in[11];
    const float* W2  = (const float*)d_in[12];
    const float* as2 = (const float*)d_in[13];
    const float* ad2 = (const float*)d_in[14];
    const float* b2  = (const float*)d_in[15];
    const float* g0  = (const float*)d_in[16];
    const float* be0 = (const float*)d_in[17];
    const float* g1  = (const float*)d_in[18];
    const float* be1 = (const float*)d_in[19];
    const float* g2  = (const float*)d_in[20];
    const float* be2 = (const float*)d_in[21];
    const float* Wqkv = (const float*)d_in[22];
    const float* bqkv = (const float*)d_in[23];
    const float* Wo  = (const float*)d_in[24];
    const float* bo  = (const float*)d_in[25];
    float* out = (float*)d_out;

    const int N = N_NODES;
    float* f = (float*)d_ws;
    const size_t NH = (size_t)N * 512;
    // fp32 buffers
    float* hA  = f;                 // [N,512] (h state A)
    float* hB  = hA + NH;           // [N,512] (h state B)
    float* xp  = hB + NH;           // [N,512]
    float* als = xp + NH;           // [N,4]
    float* ald = als + (size_t)N * 4;
    float* qkv = hA;                // reuse hA+hB region after GAT loop (61MB<82MB)
    // int buffers
    int* row_start  = (int*)(ald + (size_t)N * 4);
    int* cursor     = row_start + (N + 1);
    int* sorted_id  = cursor + N;
    int* sorted_src = sorted_id + ETOT;
    // bf16 buffers
    unsigned short* x16  = (unsigned short*)(sorted_src + ETOT);
    unsigned short* h16n = x16 + (size_t)NPAD * 128;         // [NPAD,128]
    unsigned short* h16w = h16n + (size_t)NPAD * 128;        // [NPAD,512]
    unsigned short* st16 = h16w + (size_t)NPAD * 512;        // [NPAD2,128]
    unsigned short* om16 = st16 + (size_t)NPAD2 * 128;       // [NPAD,128]
    unsigned short* w16  = om16 + (size_t)NPAD * 128;        // weights
    unsigned short* Wp16   = w16;
    unsigned short* W016   = Wp16 + 128 * 128;
    unsigned short* W116   = W016 + 512 * 128;
    unsigned short* W216   = W116 + 512 * 512;
    unsigned short* Wqkv16 = W216 + 128 * 512;
    unsigned short* Wo16   = Wqkv16 + 384 * 128;

    // ---- zero bf16 activation mirrors (pad rows must be 0 for GEMM loads) ----
    size_t bfbytes = (size_t)((char*)(w16) - (char*)x16);
    hipMemsetAsync(x16, 0, bfbytes, stream);

    // ---- weight conversions ----
    conv_bf16<<<(128 * 128 + 255) / 256, 256, 0, stream>>>(Wp, Wp16, 128 * 128);
    conv_bf16<<<(512 * 128 + 255) / 256, 256, 0, stream>>>(W0, W016, 512 * 128);
    conv_bf16<<<(512 * 512 + 255) / 256, 256, 0, stream>>>(W1, W116, 512 * 512);
    conv_bf16<<<(128 * 512 + 255) / 256, 256, 0, stream>>>(W2, W216, 128 * 512);
    conv_bf16<<<(384 * 128 + 255) / 256, 256, 0, stream>>>(Wqkv, Wqkv16, 384 * 128);
    conv_bf16<<<(128 * 128 + 255) / 256, 256, 0, stream>>>(Wo, Wo16, 128 * 128);
    conv_bf16<<<(N * 128 + 255) / 256, 256, 0, stream>>>(x, x16, N * 128);

    // ---- edge preprocessing ----
    hipMemsetAsync(cursor, 0, N * sizeof(int), stream);
    hist_kernel<<<1024, 256, 0, stream>>>(ei, cursor);
    scan_kernel<<<1, 1024, 0, stream>>>(cursor, row_start);
    scatter_kernel<<<1024, 256, 0, stream>>>(ei, cursor, sorted_id);
    segsort_kernel<<<(N + 255) / 256, 256, 0, stream>>>(ei, row_start, sorted_id,
                                                        sorted_src);

    const int GX = NPAD / 128;  // 157
    // ---- input projection -> hA fp32 [N,128] + h16n mirror ----
    {
        dim3 g(GX, 1);
        gemm_mfma<<<g, 256, 0, stream>>>(x16, Wp16, bp, hA, h16n, N, 128, 128);
    }

    float* cur = hA;
    float* nxt = hB;
    for (int t = 0; t < 2; t++) {
        // layer 0: 128 -> 512 (4 heads)
        {
            dim3 g(GX, 4);
            gemm_mfma<<<g, 256, 0, stream>>>(h16n, W016, nullptr, xp, nullptr, N, 128, 512);
            attn_coef<4><<<(N * 64 + 255) / 256, 256, 0, stream>>>(xp, as0, ad0, als, ald);
            gat_aggregate<512, 4, 0><<<N, 256, 0, stream>>>(
                xp, als, ald, row_start, sorted_src, b0, g0, be0, nullptr, nxt,
                h16w, nullptr, 0);
            float* tmp = cur; cur = nxt; nxt = tmp;
        }
        // layer 1: 512 -> 512 (4 heads), residual
        {
            dim3 g(GX, 4);
            gemm_mfma<<<g, 256, 0, stream>>>(h16w, W116, nullptr, xp, nullptr, N, 512, 512);
            attn_coef<4><<<(N * 64 + 255) / 256, 256, 0, stream>>>(xp, as1, ad1, als, ald);
            gat_aggregate<512, 4, 1><<<N, 256, 0, stream>>>(
                xp, als, ald, row_start, sorted_src, b1, g1, be1, cur, nxt,
                h16w, nullptr, 0);
            float* tmp = cur; cur = nxt; nxt = tmp;
        }
        // layer 2: 512 -> 128 (1 head), pooled residual
        {
            dim3 g(GX, 1);
            gemm_mfma<<<g, 256, 0, stream>>>(h16w, W216, nullptr, xp, nullptr, N, 512, 128);
            attn_coef<1><<<(N * 64 + 255) / 256, 256, 0, stream>>>(xp, as2, ad2, als, ald);
            gat_aggregate<128, 1, 2><<<N, 64, 0, stream>>>(
                xp, als, ald, row_start, sorted_src, b2, g2, be2, cur, nxt,
                h16n, st16 + (size_t)t * 128, 256);
            float* tmp = cur; cur = nxt; nxt = tmp;
        }
    }

    // ---- temporal attention ----
    {
        dim3 g(NPAD2 / 128, 3);
        gemm_mfma<<<g, 256, 0, stream>>>(st16, Wqkv16, bqkv, qkv, nullptr, 2 * N, 128, 384);
    }
    temporal_attn<<<N, 128, 0, stream>>>(qkv, om16);
    {
        dim3 g(GX, 1);
        gemm_mfma<<<g, 256, 0, stream>>>(om16, Wo16, bo, out, nullptr, N, 128, 128);
    }
}

// Round 6
// 847.905 us; speedup vs baseline: 1.4301x; 1.0708x over previous
//
#include <hip/hip_runtime.h>
#include <math.h>

#define N_NODES 20000
#define N_EDGES 256000
#define ETOT (N_EDGES + N_NODES)
#define NPAD 20096    // 157*128
#define NPAD2 40064   // 313*128 (2N rows padded)
#define NBLK_SCAN ((N_NODES + 255) / 256)   // 79

typedef __attribute__((ext_vector_type(8))) short bf16x8;
typedef __attribute__((ext_vector_type(4))) float f32x4;

__device__ __forceinline__ unsigned short f2bf(float f) {
    unsigned int u = __builtin_bit_cast(unsigned int, f);
    u = (u + 0x7fff + ((u >> 16) & 1)) >> 16;
    return (unsigned short)u;
}

__device__ __forceinline__ void gload_lds16(const void* g, void* l) {
    __builtin_amdgcn_global_load_lds(
        (const __attribute__((address_space(1))) void*)g,
        (__attribute__((address_space(3))) void*)l, 16, 0, 0);
}

// ---------------------------------------------------------------------------
// Edge preprocessing: counting sort by dst, deterministic order within segment
// ---------------------------------------------------------------------------

__global__ void hist_kernel(const int* __restrict__ ei, int* __restrict__ cnt) {
    for (int e = blockIdx.x * blockDim.x + threadIdx.x; e < ETOT;
         e += gridDim.x * blockDim.x) {
        int d = (e < N_EDGES) ? ei[N_EDGES + e] : (e - N_EDGES);
        atomicAdd(&cnt[d], 1);
    }
}

// 3-phase parallel exclusive scan over the 20000 per-node counts.
__global__ __launch_bounds__(256) void scanA(const int* __restrict__ cnt,
                                             int* __restrict__ incl,  // row_start+1
                                             int* __restrict__ bsum) {
    __shared__ int sh[256];
    int t = threadIdx.x;
    int i = blockIdx.x * 256 + t;
    int v = (i < N_NODES) ? cnt[i] : 0;
    sh[t] = v;
    __syncthreads();
#pragma unroll
    for (int off = 1; off < 256; off <<= 1) {
        int u = (t >= off) ? sh[t - off] : 0;
        __syncthreads();
        sh[t] += u;
        __syncthreads();
    }
    if (i < N_NODES) incl[i] = sh[t];
    if (t == 255) bsum[blockIdx.x] = sh[255];
}

__global__ void scanB(int* __restrict__ bsum, int* __restrict__ row_start) {
    if (threadIdx.x == 0) {
        int s = 0;
        for (int i = 0; i < NBLK_SCAN; i++) { int v = bsum[i]; bsum[i] = s; s += v; }
        row_start[0] = 0;
    }
}

__global__ __launch_bounds__(256) void scanC(int* __restrict__ cursor,
                                             int* __restrict__ row_start,
                                             const int* __restrict__ bsum) {
    int i = blockIdx.x * 256 + threadIdx.x;
    if (i < N_NODES) {
        int incl = row_start[i + 1] + bsum[blockIdx.x];
        row_start[i + 1] = incl;
        cursor[i] = incl - cursor[i];  // exclusive start (scatter cursor)
    }
}

__global__ void scatter_kernel(const int* __restrict__ ei, int* __restrict__ cursor,
                               int* __restrict__ sorted_id) {
    for (int e = blockIdx.x * blockDim.x + threadIdx.x; e < ETOT;
         e += gridDim.x * blockDim.x) {
        int d = (e < N_EDGES) ? ei[N_EDGES + e] : (e - N_EDGES);
        int pos = atomicAdd(&cursor[d], 1);
        sorted_id[pos] = e;
    }
}

// Deterministic order: insertion-sort each node's segment by edge id.
__global__ void segsort_kernel(const int* __restrict__ ei,
                               const int* __restrict__ row_start,
                               int* __restrict__ sorted_id,
                               int* __restrict__ sorted_src) {
    int n = blockIdx.x * blockDim.x + threadIdx.x;
    if (n >= N_NODES) return;
    int s = row_start[n], e = row_start[n + 1];
    for (int i = s + 1; i < e; i++) {
        int v = sorted_id[i];
        int j = i - 1;
        while (j >= s && sorted_id[j] > v) { sorted_id[j + 1] = sorted_id[j]; j--; }
        sorted_id[j + 1] = v;
    }
    for (int i = s; i < e; i++) {
        int id = sorted_id[i];
        sorted_src[i] = (id < N_EDGES) ? ei[id] : (id - N_EDGES);
    }
}

// ---------------------------------------------------------------------------
// bf16 conversion + pad-row zeroing
// ---------------------------------------------------------------------------
__global__ void conv_bf16(const float* __restrict__ src,
                          unsigned short* __restrict__ dst, int n) {
    int i = blockIdx.x * blockDim.x + threadIdx.x;
    if (i < n) dst[i] = f2bf(src[i]);
}

__global__ void zero_pads(unsigned short* x16, unsigned short* h16n,
                          unsigned short* h16w, unsigned short* st16,
                          unsigned short* om16) {
    int i = blockIdx.x * blockDim.x + threadIdx.x;
    const int PR = NPAD - N_NODES;  // 96 pad rows
    if (i < PR * 128) {
        x16[(size_t)N_NODES * 128 + i] = 0;
        h16n[(size_t)N_NODES * 128 + i] = 0;
        om16[(size_t)N_NODES * 128 + i] = 0;
    }
    if (i < PR * 512) h16w[(size_t)N_NODES * 512 + i] = 0;
    if (i < (NPAD2 - 2 * N_NODES) * 128) st16[(size_t)(2 * N_NODES) * 128 + i] = 0;
}

// ---------------------------------------------------------------------------
// bf16 MFMA GEMM:  C[r,c] = sum_k A[r,k]*B[c,k] (+bias[c]), optionally fused
// GAT attention coefficients: al_s[r,H=blockIdx.y] = dot(C_row_headslice, a_s).
// Each y-block covers exactly one head (128 cols).  128x128 tile, BK=64,
// 4 waves, mfma_f32_16x16x32_bf16.
// ---------------------------------------------------------------------------
__global__ __launch_bounds__(256) void gemm_mfma(
    const unsigned short* __restrict__ A, const unsigned short* __restrict__ B,
    const float* __restrict__ bias, float* __restrict__ Cf,
    unsigned short* __restrict__ C16, int R, int K, int ldc,
    const float* __restrict__ a_s, const float* __restrict__ a_d,
    float* __restrict__ al_s, float* __restrict__ al_d, int H) {
    __shared__ unsigned short Al[128 * 64];
    __shared__ unsigned short Bl[128 * 64];
    __shared__ float red_s[4][64], red_d[4][64];
    int tid = threadIdx.x;
    int lane = tid & 63, wv = tid >> 6;
    int wr = (wv >> 1) * 64, wc = (wv & 1) * 64;
    size_t br = (size_t)blockIdx.x * 128;
    size_t bc = (size_t)blockIdx.y * 128;
    f32x4 acc[4][4] = {};
    for (int k0 = 0; k0 < K; k0 += 64) {
#pragma unroll
        for (int i = 0; i < 4; i++) {
            int idx = i * 256 + tid;
            int row = idx >> 3;
            int kb = (idx & 7) << 4;
            gload_lds16((const char*)(A + (br + row) * K + k0) + kb,
                        (char*)Al + idx * 16);
            gload_lds16((const char*)(B + (bc + row) * K + k0) + kb,
                        (char*)Bl + idx * 16);
        }
        __syncthreads();
#pragma unroll
        for (int kk = 0; kk < 2; kk++) {
            bf16x8 af[4], bfr[4];
#pragma unroll
            for (int m = 0; m < 4; m++)
                af[m] = *(const bf16x8*)&Al[(wr + m * 16 + (lane & 15)) * 64 +
                                            kk * 32 + (lane >> 4) * 8];
#pragma unroll
            for (int n = 0; n < 4; n++)
                bfr[n] = *(const bf16x8*)&Bl[(wc + n * 16 + (lane & 15)) * 64 +
                                             kk * 32 + (lane >> 4) * 8];
#pragma unroll
            for (int m = 0; m < 4; m++)
#pragma unroll
                for (int n = 0; n < 4; n++)
                    acc[m][n] = __builtin_amdgcn_mfma_f32_16x16x32_bf16(
                        af[m], bfr[n], acc[m][n], 0, 0, 0);
        }
        __syncthreads();
    }

    // ---- fused attention-coefficient epilogue (deterministic reduction) ----
    if (al_s) {
        float asr[4], adr[4];
#pragma unroll
        for (int n = 0; n < 4; n++) {
            int c = (int)bc + wc + n * 16 + (lane & 15);
            asr[n] = a_s[c];
            adr[n] = a_d[c];
        }
        float ps[4][4], pd[4][4];
#pragma unroll
        for (int m = 0; m < 4; m++)
#pragma unroll
            for (int j = 0; j < 4; j++) {
                float s = 0.f, d = 0.f;
#pragma unroll
                for (int n = 0; n < 4; n++) {
                    float v = acc[m][n][j];
                    s = fmaf(v, asr[n], s);
                    d = fmaf(v, adr[n], d);
                }
#pragma unroll
                for (int off = 8; off; off >>= 1) {
                    s += __shfl_xor(s, off);
                    d += __shfl_xor(d, off);
                }
                ps[m][j] = s;
                pd[m][j] = d;
            }
        if ((lane & 15) == 0) {
#pragma unroll
            for (int m = 0; m < 4; m++)
#pragma unroll
                for (int j = 0; j < 4; j++) {
                    int lr = m * 16 + (lane >> 4) * 4 + j;
                    red_s[wv][lr] = ps[m][j];
                    red_d[wv][lr] = pd[m][j];
                }
        }
        __syncthreads();
        if (tid < 128) {
            int half = tid >> 6, lr = tid & 63;
            float s = red_s[half * 2][lr] + red_s[half * 2 + 1][lr];
            float d = red_d[half * 2][lr] + red_d[half * 2 + 1][lr];
            size_t r = br + tid;
            if (r < (size_t)R) {
                al_s[r * H + blockIdx.y] = s;
                al_d[r * H + blockIdx.y] = d;
            }
        }
    }

    // ---- C write ----
#pragma unroll
    for (int m = 0; m < 4; m++) {
        int r0 = wr + m * 16 + (lane >> 4) * 4;
#pragma unroll
        for (int n = 0; n < 4; n++) {
            int c = (int)bc + wc + n * 16 + (lane & 15);
            float bv = bias ? bias[c] : 0.f;
#pragma unroll
            for (int j = 0; j < 4; j++) {
                size_t r = br + r0 + j;
                if (r < (size_t)R) {
                    float v = acc[m][n][j] + bv;
                    if (Cf) Cf[r * ldc + c] = v;
                    if (C16) C16[r * ldc + c] = f2bf(v);
                }
            }
        }
    }
}

// ---------------------------------------------------------------------------
// Fused GAT aggregation + bias + ELU + LayerNorm + residual (+bf16 mirrors).
// One block per node, C/2 threads; thread owns channels (2*tid, 2*tid+1) so
// the per-edge gather is one dwordx2 and the head index is wave-uniform.
// ---------------------------------------------------------------------------
template <int C, int HEADS, int RES>
__global__ __launch_bounds__(C / 2) void gat_aggregate(
    const float* __restrict__ xp, const float* __restrict__ al_s,
    const float* __restrict__ al_d, const int* __restrict__ row_start,
    const int* __restrict__ srcs, const float* __restrict__ bias,
    const float* __restrict__ gamma, const float* __restrict__ beta,
    const float* __restrict__ h_res, float* __restrict__ out,
    unsigned short* __restrict__ out16, unsigned short* __restrict__ out2_16,
    int out2_stride) {
    const int BLK = C / 2;
    const int NW = BLK / 64;
    int n = blockIdx.x;
    int tid = threadIdx.x;
    int lane = tid & 63, wv = tid >> 6;
    __shared__ float m_sh[HEADS], s_sh[HEADS];
    __shared__ int src_sh[64];
    __shared__ float w_sh[64 * HEADS];
    __shared__ float red_sh[2 * NW];
    int base = row_start[n];
    int deg = row_start[n + 1] - base;

    // ---- segment softmax stats ----
    for (int h = wv; h < HEADS; h += NW) {
        float ald = al_d[n * HEADS + h];
        float m = -3.4e38f;
        for (int e = lane; e < deg; e += 64) {
            float v = al_s[srcs[base + e] * HEADS + h] + ald;
            v = v > 0.f ? v : 0.2f * v;
            m = fmaxf(m, v);
        }
#pragma unroll
        for (int off = 32; off; off >>= 1) m = fmaxf(m, __shfl_xor(m, off));
        float s = 0.f;
        for (int e = lane; e < deg; e += 64) {
            float v = al_s[srcs[base + e] * HEADS + h] + ald;
            v = v > 0.f ? v : 0.2f * v;
            s += expf(v - m);
        }
#pragma unroll
        for (int off = 32; off; off >>= 1) s += __shfl_xor(s, off);
        if (lane == 0) { m_sh[h] = m; s_sh[h] = s + 1e-16f; }
    }
    __syncthreads();

    // ---- weighted message accumulation ----
    float acc0 = 0.f, acc1 = 0.f;
    const int c0 = 2 * tid, c1 = c0 + 1;
    const int h = (HEADS == 1) ? 0 : (c0 >> 7);  // wave-uniform
    for (int cb = 0; cb < deg; cb += 64) {
        int clen = min(64, deg - cb);
        if (tid < clen) src_sh[tid] = srcs[base + cb + tid];
        __syncthreads();
        if (tid < clen * HEADS) {
            int e = tid / HEADS, hh = tid % HEADS;
            int sidx = src_sh[e];
            float v = al_s[sidx * HEADS + hh] + al_d[n * HEADS + hh];
            v = v > 0.f ? v : 0.2f * v;
            w_sh[tid] = expf(v - m_sh[hh]) / s_sh[hh];
        }
        __syncthreads();
        for (int j = 0; j < clen; j++) {
            const float2 v =
                *reinterpret_cast<const float2*>(&xp[(size_t)src_sh[j] * C + c0]);
            float w = w_sh[j * HEADS + h];
            acc0 = fmaf(w, v.x, acc0);
            acc1 = fmaf(w, v.y, acc1);
        }
        __syncthreads();
    }

    // ---- epilogue: +bias, ELU, LayerNorm, residual ----
    float2 bv = *reinterpret_cast<const float2*>(&bias[c0]);
    float v0 = acc0 + bv.x;
    float v1 = acc1 + bv.y;
    v0 = v0 > 0.f ? v0 : expm1f(v0);
    v1 = v1 > 0.f ? v1 : expm1f(v1);
    float s = v0 + v1, q = v0 * v0 + v1 * v1;
#pragma unroll
    for (int off = 32; off; off >>= 1) {
        s += __shfl_xor(s, off);
        q += __shfl_xor(q, off);
    }
    if (NW > 1) {
        if (lane == 0) { red_sh[wv * 2] = s; red_sh[wv * 2 + 1] = q; }
        __syncthreads();
        s = 0.f; q = 0.f;
#pragma unroll
        for (int w = 0; w < NW; w++) { s += red_sh[w * 2]; q += red_sh[w * 2 + 1]; }
    }
    float mu = s / C;
    float var = q / C - mu * mu;
    float rstd = 1.0f / sqrtf(var + 1e-5f);
    float2 gv = *reinterpret_cast<const float2*>(&gamma[c0]);
    float2 bev = *reinterpret_cast<const float2*>(&beta[c0]);
    v0 = (v0 - mu) * rstd * gv.x + bev.x;
    v1 = (v1 - mu) * rstd * gv.y + bev.y;
    if (RES == 1) {
        float2 rv = *reinterpret_cast<const float2*>(&h_res[(size_t)n * C + c0]);
        v0 += rv.x;
        v1 += rv.y;
    } else if (RES == 2) {
        const float4 r0 = *reinterpret_cast<const float4*>(&h_res[(size_t)n * C * 4 + 4 * c0]);
        const float4 r1 = *reinterpret_cast<const float4*>(&h_res[(size_t)n * C * 4 + 4 * c1]);
        v0 += 0.25f * (r0.x + r0.y + r0.z + r0.w);
        v1 += 0.25f * (r1.x + r1.y + r1.z + r1.w);
    }
    *reinterpret_cast<float2*>(&out[(size_t)n * C + c0]) = make_float2(v0, v1);
    if (out16) {
        ushort2 o = {f2bf(v0), f2bf(v1)};
        *reinterpret_cast<ushort2*>(&out16[(size_t)n * C + c0]) = o;
    }
    if (out2_16) {
        ushort2 o = {f2bf(v0), f2bf(v1)};
        *reinterpret_cast<ushort2*>(&out2_16[(size_t)n * out2_stride + c0]) = o;
    }
}

// ---------------------------------------------------------------------------
// Temporal self-attention over T=2 states. qkv:[2N,384] fp32 -> om16:[N,128] bf16
// ---------------------------------------------------------------------------
__global__ __launch_bounds__(128) void temporal_attn(const float* __restrict__ qkv,
                                                     unsigned short* __restrict__ om16) {
    __shared__ float sh[768];
    int n = blockIdx.x;
    int c = threadIdx.x;
    for (int i = c; i < 768; i += 128) {
        int t = i / 384;
        sh[i] = qkv[(size_t)(n * 2 + t) * 384 + (i - t * 384)];
    }
    __syncthreads();
    int head = c >> 5;
    int hb = head * 32;
    const float scale = 0.17677669529663687f;
    float o[2];
#pragma unroll
    for (int qt = 0; qt < 2; qt++) {
        float s0 = 0.f, s1 = 0.f;
#pragma unroll
        for (int d = 0; d < 32; d++) {
            float qv = sh[qt * 384 + hb + d];
            s0 = fmaf(qv, sh[0 * 384 + 128 + hb + d], s0);
            s1 = fmaf(qv, sh[1 * 384 + 128 + hb + d], s1);
        }
        s0 *= scale; s1 *= scale;
        float m = fmaxf(s0, s1);
        float p0 = expf(s0 - m), p1 = expf(s1 - m);
        float inv = 1.0f / (p0 + p1);
        o[qt] = p0 * inv * sh[0 * 384 + 256 + c] + p1 * inv * sh[1 * 384 + 256 + c];
    }
    om16[(size_t)n * 128 + c] = f2bf(0.5f * (o[0] + o[1]));
}

// ---------------------------------------------------------------------------

extern "C" void kernel_launch(void* const* d_in, const int* in_sizes, int n_in,
                              void* d_out, int out_size, void* d_ws, size_t ws_size,
                              hipStream_t stream) {
    const float* x   = (const float*)d_in[0];
    const int*   ei  = (const int*)d_in[1];
    const float* Wp  = (const float*)d_in[2];
    const float* bp  = (const float*)d_in[3];
    const float* W0  = (const float*)d_in[4];
    const float* as0 = (const float*)d_in[5];
    const float* ad0 = (const float*)d_in[6];
    const float* b0  = (const float*)d_in[7];
    const float* W1  = (const float*)d_in[8];
    const float* as1 = (const float*)d_in[9];
    const float* ad1 = (const float*)d_in[10];
    const float* b1  = (const float*)d_in[11];
    const float* W2  = (const float*)d_in[12];
    const float* as2 = (const float*)d_in[13];
    const float* ad2 = (const float*)d_in[14];
    const float* b2  = (const float*)d_in[15];
    const float* g0  = (const float*)d_in[16];
    const float* be0 = (const float*)d_in[17];
    const float* g1  = (const float*)d_in[18];
    const float* be1 = (const float*)d_in[19];
    const float* g2  = (const float*)d_in[20];
    const float* be2 = (const float*)d_in[21];
    const float* Wqkv = (const float*)d_in[22];
    const float* bqkv = (const float*)d_in[23];
    const float* Wo  = (const float*)d_in[24];
    const float* bo  = (const float*)d_in[25];
    float* out = (float*)d_out;

    const int N = N_NODES;
    float* f = (float*)d_ws;
    const size_t NH = (size_t)N * 512;
    // fp32 buffers
    float* hA  = f;                 // [N,512]
    float* hB  = hA + NH;           // [N,512]
    float* xp  = hB + NH;           // [N,512]
    float* als = xp + NH;           // [N,4]
    float* ald = als + (size_t)N * 4;
    float* qkv = hA;                // reuse hA+hB region after GAT loop
    // int buffers
    int* row_start  = (int*)(ald + (size_t)N * 4);
    int* cursor     = row_start + (N + 1);
    int* sorted_id  = cursor + N;
    int* sorted_src = sorted_id + ETOT;
    int* bsum       = sorted_src + ETOT;          // NBLK_SCAN
    // bf16 buffers
    unsigned short* x16  = (unsigned short*)(bsum + NBLK_SCAN + 1);
    unsigned short* h16n = x16 + (size_t)NPAD * 128;         // [NPAD,128]
    unsigned short* h16w = h16n + (size_t)NPAD * 128;        // [NPAD,512]
    unsigned short* st16 = h16w + (size_t)NPAD * 512;        // [NPAD2,128]
    unsigned short* om16 = st16 + (size_t)NPAD2 * 128;       // [NPAD,128]
    unsigned short* w16  = om16 + (size_t)NPAD * 128;
    unsigned short* Wp16   = w16;
    unsigned short* W016   = Wp16 + 128 * 128;
    unsigned short* W116   = W016 + 512 * 128;
    unsigned short* W216   = W116 + 512 * 512;
    unsigned short* Wqkv16 = W216 + 128 * 512;
    unsigned short* Wo16   = Wqkv16 + 384 * 128;

    // ---- zero pad rows of bf16 mirrors (every call; deterministic) ----
    zero_pads<<<192, 256, 0, stream>>>(x16, h16n, h16w, st16, om16);

    // ---- weight conversions ----
    conv_bf16<<<(128 * 128 + 255) / 256, 256, 0, stream>>>(Wp, Wp16, 128 * 128);
    conv_bf16<<<(512 * 128 + 255) / 256, 256, 0, stream>>>(W0, W016, 512 * 128);
    conv_bf16<<<(512 * 512 + 255) / 256, 256, 0, stream>>>(W1, W116, 512 * 512);
    conv_bf16<<<(128 * 512 + 255) / 256, 256, 0, stream>>>(W2, W216, 128 * 512);
    conv_bf16<<<(384 * 128 + 255) / 256, 256, 0, stream>>>(Wqkv, Wqkv16, 384 * 128);
    conv_bf16<<<(128 * 128 + 255) / 256, 256, 0, stream>>>(Wo, Wo16, 128 * 128);
    conv_bf16<<<(N * 128 + 255) / 256, 256, 0, stream>>>(x, x16, N * 128);

    // ---- edge preprocessing (deterministic counting sort by dst) ----
    hipMemsetAsync(cursor, 0, N * sizeof(int), stream);
    hist_kernel<<<1024, 256, 0, stream>>>(ei, cursor);
    scanA<<<NBLK_SCAN, 256, 0, stream>>>(cursor, row_start + 1, bsum);
    scanB<<<1, 64, 0, stream>>>(bsum, row_start);
    scanC<<<NBLK_SCAN, 256, 0, stream>>>(cursor, row_start, bsum);
    scatter_kernel<<<1024, 256, 0, stream>>>(ei, cursor, sorted_id);
    segsort_kernel<<<(N + 255) / 256, 256, 0, stream>>>(ei, row_start, sorted_id,
                                                        sorted_src);

    const int GX = NPAD / 128;  // 157
    // ---- input projection -> hA fp32 + h16n mirror ----
    {
        dim3 g(GX, 1);
        gemm_mfma<<<g, 256, 0, stream>>>(x16, Wp16, bp, hA, h16n, N, 128, 128,
                                         nullptr, nullptr, nullptr, nullptr, 0);
    }

    float* cur = hA;
    float* nxt = hB;
    for (int t = 0; t < 2; t++) {
        // layer 0: 128 -> 512 (4 heads)
        {
            dim3 g(GX, 4);
            gemm_mfma<<<g, 256, 0, stream>>>(h16n, W016, nullptr, xp, nullptr,
                                             N, 128, 512, as0, ad0, als, ald, 4);
            gat_aggregate<512, 4, 0><<<N, 256, 0, stream>>>(
                xp, als, ald, row_start, sorted_src, b0, g0, be0, nullptr, nxt,
                h16w, nullptr, 0);
            float* tmp = cur; cur = nxt; nxt = tmp;
        }
        // layer 1: 512 -> 512 (4 heads), residual
        {
            dim3 g(GX, 4);
            gemm_mfma<<<g, 256, 0, stream>>>(h16w, W116, nullptr, xp, nullptr,
                                             N, 512, 512, as1, ad1, als, ald, 4);
            gat_aggregate<512, 4, 1><<<N, 256, 0, stream>>>(
                xp, als, ald, row_start, sorted_src, b1, g1, be1, cur, nxt,
                h16w, nullptr, 0);
            float* tmp = cur; cur = nxt; nxt = tmp;
        }
        // layer 2: 512 -> 128 (1 head), pooled residual
        {
            dim3 g(GX, 1);
            gemm_mfma<<<g, 256, 0, stream>>>(h16w, W216, nullptr, xp, nullptr,
                                             N, 512, 128, as2, ad2, als, ald, 1);
            gat_aggregate<128, 1, 2><<<N, 64, 0, stream>>>(
                xp, als, ald, row_start, sorted_src, b2, g2, be2, cur, nxt,
                h16n, st16 + (size_t)t * 128, 256);
            float* tmp = cur; cur = nxt; nxt = tmp;
        }
    }

    // ---- temporal attention ----
    {
        dim3 g(NPAD2 / 128, 3);
        gemm_mfma<<<g, 256, 0, stream>>>(st16, Wqkv16, bqkv, qkv, nullptr,
                                         2 * N, 128, 384, nullptr, nullptr,
                                         nullptr, nullptr, 0);
    }
    temporal_attn<<<N, 128, 0, stream>>>(qkv, om16);
    {
        dim3 g(GX, 1);
        gemm_mfma<<<g, 256, 0, stream>>>(om16, Wo16, bo, out, N != 0 ? nullptr : nullptr,
                                         N, 128, 128, nullptr, nullptr,
                                         nullptr, nullptr, 0);
    }
}

// Round 7
// 798.607 us; speedup vs baseline: 1.5184x; 1.0617x over previous
//
#include <hip/hip_runtime.h>
#include <math.h>

#define N_NODES 20000
#define N_EDGES 256000
#define ETOT (N_EDGES + N_NODES)
#define NPAD 20096    // 157*128
#define NPAD2 40064   // 313*128 (2N rows padded)
#define NBLK_SCAN ((N_NODES + 255) / 256)   // 79

typedef __attribute__((ext_vector_type(8))) short bf16x8;
typedef __attribute__((ext_vector_type(4))) float f32x4;

__device__ __forceinline__ unsigned short f2bf(float f) {
    unsigned int u = __builtin_bit_cast(unsigned int, f);
    u = (u + 0x7fff + ((u >> 16) & 1)) >> 16;
    return (unsigned short)u;
}

__device__ __forceinline__ float bf2f(unsigned short u) {
    return __builtin_bit_cast(float, (unsigned int)u << 16);
}

__device__ __forceinline__ void gload_lds16(const void* g, void* l) {
    __builtin_amdgcn_global_load_lds(
        (const __attribute__((address_space(1))) void*)g,
        (__attribute__((address_space(3))) void*)l, 16, 0, 0);
}

// ---------------------------------------------------------------------------
// Edge preprocessing: counting sort by dst, deterministic order within segment
// ---------------------------------------------------------------------------

__global__ void hist_kernel(const int* __restrict__ ei, int* __restrict__ cnt) {
    for (int e = blockIdx.x * blockDim.x + threadIdx.x; e < ETOT;
         e += gridDim.x * blockDim.x) {
        int d = (e < N_EDGES) ? ei[N_EDGES + e] : (e - N_EDGES);
        atomicAdd(&cnt[d], 1);
    }
}

__global__ __launch_bounds__(256) void scanA(const int* __restrict__ cnt,
                                             int* __restrict__ incl,
                                             int* __restrict__ bsum) {
    __shared__ int sh[256];
    int t = threadIdx.x;
    int i = blockIdx.x * 256 + t;
    int v = (i < N_NODES) ? cnt[i] : 0;
    sh[t] = v;
    __syncthreads();
#pragma unroll
    for (int off = 1; off < 256; off <<= 1) {
        int u = (t >= off) ? sh[t - off] : 0;
        __syncthreads();
        sh[t] += u;
        __syncthreads();
    }
    if (i < N_NODES) incl[i] = sh[t];
    if (t == 255) bsum[blockIdx.x] = sh[255];
}

__global__ void scanB(int* __restrict__ bsum, int* __restrict__ row_start) {
    if (threadIdx.x == 0) {
        int s = 0;
        for (int i = 0; i < NBLK_SCAN; i++) { int v = bsum[i]; bsum[i] = s; s += v; }
        row_start[0] = 0;
    }
}

__global__ __launch_bounds__(256) void scanC(int* __restrict__ cursor,
                                             int* __restrict__ row_start,
                                             const int* __restrict__ bsum) {
    int i = blockIdx.x * 256 + threadIdx.x;
    if (i < N_NODES) {
        int incl = row_start[i + 1] + bsum[blockIdx.x];
        row_start[i + 1] = incl;
        cursor[i] = incl - cursor[i];
    }
}

__global__ void scatter_kernel(const int* __restrict__ ei, int* __restrict__ cursor,
                               int* __restrict__ sorted_id) {
    for (int e = blockIdx.x * blockDim.x + threadIdx.x; e < ETOT;
         e += gridDim.x * blockDim.x) {
        int d = (e < N_EDGES) ? ei[N_EDGES + e] : (e - N_EDGES);
        int pos = atomicAdd(&cursor[d], 1);
        sorted_id[pos] = e;
    }
}

__global__ void segsort_kernel(const int* __restrict__ ei,
                               const int* __restrict__ row_start,
                               int* __restrict__ sorted_id,
                               int* __restrict__ sorted_src) {
    int n = blockIdx.x * blockDim.x + threadIdx.x;
    if (n >= N_NODES) return;
    int s = row_start[n], e = row_start[n + 1];
    for (int i = s + 1; i < e; i++) {
        int v = sorted_id[i];
        int j = i - 1;
        while (j >= s && sorted_id[j] > v) { sorted_id[j + 1] = sorted_id[j]; j--; }
        sorted_id[j + 1] = v;
    }
    for (int i = s; i < e; i++) {
        int id = sorted_id[i];
        sorted_src[i] = (id < N_EDGES) ? ei[id] : (id - N_EDGES);
    }
}

// ---------------------------------------------------------------------------
// bf16 conversion + pad-row zeroing
// ---------------------------------------------------------------------------
__global__ void conv_bf16(const float* __restrict__ src,
                          unsigned short* __restrict__ dst, int n) {
    int i = blockIdx.x * blockDim.x + threadIdx.x;
    if (i < n) dst[i] = f2bf(src[i]);
}

__global__ void zero_pads(unsigned short* x16, unsigned short* h16n,
                          unsigned short* h16w, unsigned short* st16,
                          unsigned short* om16) {
    int i = blockIdx.x * blockDim.x + threadIdx.x;
    const int PR = NPAD - N_NODES;  // 96 pad rows
    if (i < PR * 128) {
        x16[(size_t)N_NODES * 128 + i] = 0;
        h16n[(size_t)N_NODES * 128 + i] = 0;
        om16[(size_t)N_NODES * 128 + i] = 0;
    }
    if (i < PR * 512) h16w[(size_t)N_NODES * 512 + i] = 0;
    if (i < (NPAD2 - 2 * N_NODES) * 128) st16[(size_t)(2 * N_NODES) * 128 + i] = 0;
}

// ---------------------------------------------------------------------------
// bf16 MFMA GEMM:  C[r,c] = sum_k A[r,k]*B[c,k] (+bias[c]), optional fused
// GAT attention-coefficient epilogue (al_s/al_d per head = blockIdx.y).
// ---------------------------------------------------------------------------
__global__ __launch_bounds__(256) void gemm_mfma(
    const unsigned short* __restrict__ A, const unsigned short* __restrict__ B,
    const float* __restrict__ bias, float* __restrict__ Cf,
    unsigned short* __restrict__ C16, int R, int K, int ldc,
    const float* __restrict__ a_s, const float* __restrict__ a_d,
    float* __restrict__ al_s, float* __restrict__ al_d, int H) {
    __shared__ unsigned short Al[128 * 64];
    __shared__ unsigned short Bl[128 * 64];
    __shared__ float red_s[4][64], red_d[4][64];
    int tid = threadIdx.x;
    int lane = tid & 63, wv = tid >> 6;
    int wr = (wv >> 1) * 64, wc = (wv & 1) * 64;
    size_t br = (size_t)blockIdx.x * 128;
    size_t bc = (size_t)blockIdx.y * 128;
    f32x4 acc[4][4] = {};
    for (int k0 = 0; k0 < K; k0 += 64) {
#pragma unroll
        for (int i = 0; i < 4; i++) {
            int idx = i * 256 + tid;
            int row = idx >> 3;
            int kb = (idx & 7) << 4;
            gload_lds16((const char*)(A + (br + row) * K + k0) + kb,
                        (char*)Al + idx * 16);
            gload_lds16((const char*)(B + (bc + row) * K + k0) + kb,
                        (char*)Bl + idx * 16);
        }
        __syncthreads();
#pragma unroll
        for (int kk = 0; kk < 2; kk++) {
            bf16x8 af[4], bfr[4];
#pragma unroll
            for (int m = 0; m < 4; m++)
                af[m] = *(const bf16x8*)&Al[(wr + m * 16 + (lane & 15)) * 64 +
                                            kk * 32 + (lane >> 4) * 8];
#pragma unroll
            for (int n = 0; n < 4; n++)
                bfr[n] = *(const bf16x8*)&Bl[(wc + n * 16 + (lane & 15)) * 64 +
                                             kk * 32 + (lane >> 4) * 8];
#pragma unroll
            for (int m = 0; m < 4; m++)
#pragma unroll
                for (int n = 0; n < 4; n++)
                    acc[m][n] = __builtin_amdgcn_mfma_f32_16x16x32_bf16(
                        af[m], bfr[n], acc[m][n], 0, 0, 0);
        }
        __syncthreads();
    }

    // ---- fused attention-coefficient epilogue ----
    if (al_s) {
        float asr[4], adr[4];
#pragma unroll
        for (int n = 0; n < 4; n++) {
            int c = (int)bc + wc + n * 16 + (lane & 15);
            asr[n] = a_s[c];
            adr[n] = a_d[c];
        }
        float ps[4][4], pd[4][4];
#pragma unroll
        for (int m = 0; m < 4; m++)
#pragma unroll
            for (int j = 0; j < 4; j++) {
                float s = 0.f, d = 0.f;
#pragma unroll
                for (int n = 0; n < 4; n++) {
                    float v = acc[m][n][j];
                    s = fmaf(v, asr[n], s);
                    d = fmaf(v, adr[n], d);
                }
#pragma unroll
                for (int off = 8; off; off >>= 1) {
                    s += __shfl_xor(s, off);
                    d += __shfl_xor(d, off);
                }
                ps[m][j] = s;
                pd[m][j] = d;
            }
        if ((lane & 15) == 0) {
#pragma unroll
            for (int m = 0; m < 4; m++)
#pragma unroll
                for (int j = 0; j < 4; j++) {
                    int lr = m * 16 + (lane >> 4) * 4 + j;
                    red_s[wv][lr] = ps[m][j];
                    red_d[wv][lr] = pd[m][j];
                }
        }
        __syncthreads();
        if (tid < 128) {
            int half = tid >> 6, lr = tid & 63;
            float s = red_s[half * 2][lr] + red_s[half * 2 + 1][lr];
            float d = red_d[half * 2][lr] + red_d[half * 2 + 1][lr];
            size_t r = br + tid;
            if (r < (size_t)R) {
                al_s[r * H + blockIdx.y] = s;
                al_d[r * H + blockIdx.y] = d;
            }
        }
    }

    // ---- C write ----
#pragma unroll
    for (int m = 0; m < 4; m++) {
        int r0 = wr + m * 16 + (lane >> 4) * 4;
#pragma unroll
        for (int n = 0; n < 4; n++) {
            int c = (int)bc + wc + n * 16 + (lane & 15);
            float bv = bias ? bias[c] : 0.f;
#pragma unroll
            for (int j = 0; j < 4; j++) {
                size_t r = br + r0 + j;
                if (r < (size_t)R) {
                    float v = acc[m][n][j] + bv;
                    if (Cf) Cf[r * ldc + c] = v;
                    if (C16) C16[r * ldc + c] = f2bf(v);
                }
            }
        }
    }
}

// ---------------------------------------------------------------------------
// Fused GAT aggregation + bias + ELU + LayerNorm + residual.
// Gathers bf16 xp rows (ushort2 per thread), fp32 accumulate.
// ---------------------------------------------------------------------------
template <int C, int HEADS, int RES>
__global__ __launch_bounds__(C / 2) void gat_aggregate(
    const unsigned short* __restrict__ xp16, const float* __restrict__ al_s,
    const float* __restrict__ al_d, const int* __restrict__ row_start,
    const int* __restrict__ srcs, const float* __restrict__ bias,
    const float* __restrict__ gamma, const float* __restrict__ beta,
    const float* __restrict__ h_res, float* __restrict__ out,
    unsigned short* __restrict__ out16, unsigned short* __restrict__ out2_16,
    int out2_stride) {
    const int BLK = C / 2;
    const int NW = BLK / 64;
    int n = blockIdx.x;
    int tid = threadIdx.x;
    int lane = tid & 63, wv = tid >> 6;
    __shared__ float m_sh[HEADS], s_sh[HEADS];
    __shared__ int src_sh[64];
    __shared__ float w_sh[64 * HEADS];
    __shared__ float red_sh[2 * NW];
    int base = row_start[n];
    int deg = row_start[n + 1] - base;

    // ---- segment softmax stats ----
    for (int h = wv; h < HEADS; h += NW) {
        float ald = al_d[n * HEADS + h];
        float m = -3.4e38f;
        for (int e = lane; e < deg; e += 64) {
            float v = al_s[srcs[base + e] * HEADS + h] + ald;
            v = v > 0.f ? v : 0.2f * v;
            m = fmaxf(m, v);
        }
#pragma unroll
        for (int off = 32; off; off >>= 1) m = fmaxf(m, __shfl_xor(m, off));
        float s = 0.f;
        for (int e = lane; e < deg; e += 64) {
            float v = al_s[srcs[base + e] * HEADS + h] + ald;
            v = v > 0.f ? v : 0.2f * v;
            s += expf(v - m);
        }
#pragma unroll
        for (int off = 32; off; off >>= 1) s += __shfl_xor(s, off);
        if (lane == 0) { m_sh[h] = m; s_sh[h] = s + 1e-16f; }
    }
    __syncthreads();

    // ---- weighted message accumulation (bf16 gather) ----
    float acc0 = 0.f, acc1 = 0.f;
    const int c0 = 2 * tid;
    const int h = (HEADS == 1) ? 0 : (c0 >> 7);  // wave-uniform
    for (int cb = 0; cb < deg; cb += 64) {
        int clen = min(64, deg - cb);
        if (tid < clen) src_sh[tid] = srcs[base + cb + tid];
        __syncthreads();
        if (tid < clen * HEADS) {
            int e = tid / HEADS, hh = tid % HEADS;
            int sidx = src_sh[e];
            float v = al_s[sidx * HEADS + hh] + al_d[n * HEADS + hh];
            v = v > 0.f ? v : 0.2f * v;
            w_sh[tid] = expf(v - m_sh[hh]) / s_sh[hh];
        }
        __syncthreads();
#pragma unroll 2
        for (int j = 0; j < clen; j++) {
            const ushort2 v =
                *reinterpret_cast<const ushort2*>(&xp16[(size_t)src_sh[j] * C + c0]);
            float w = w_sh[j * HEADS + h];
            acc0 = fmaf(w, bf2f(v.x), acc0);
            acc1 = fmaf(w, bf2f(v.y), acc1);
        }
        __syncthreads();
    }

    // ---- epilogue: +bias, ELU, LayerNorm, residual ----
    float2 bv = *reinterpret_cast<const float2*>(&bias[c0]);
    float v0 = acc0 + bv.x;
    float v1 = acc1 + bv.y;
    v0 = v0 > 0.f ? v0 : expm1f(v0);
    v1 = v1 > 0.f ? v1 : expm1f(v1);
    float s = v0 + v1, q = v0 * v0 + v1 * v1;
#pragma unroll
    for (int off = 32; off; off >>= 1) {
        s += __shfl_xor(s, off);
        q += __shfl_xor(q, off);
    }
    if (NW > 1) {
        if (lane == 0) { red_sh[wv * 2] = s; red_sh[wv * 2 + 1] = q; }
        __syncthreads();
        s = 0.f; q = 0.f;
#pragma unroll
        for (int w = 0; w < NW; w++) { s += red_sh[w * 2]; q += red_sh[w * 2 + 1]; }
    }
    float mu = s / C;
    float var = q / C - mu * mu;
    float rstd = 1.0f / sqrtf(var + 1e-5f);
    float2 gv = *reinterpret_cast<const float2*>(&gamma[c0]);
    float2 bev = *reinterpret_cast<const float2*>(&beta[c0]);
    v0 = (v0 - mu) * rstd * gv.x + bev.x;
    v1 = (v1 - mu) * rstd * gv.y + bev.y;
    if (RES == 1) {
        float2 rv = *reinterpret_cast<const float2*>(&h_res[(size_t)n * C + c0]);
        v0 += rv.x;
        v1 += rv.y;
    } else if (RES == 2) {
        const float4 r0 = *reinterpret_cast<const float4*>(&h_res[(size_t)n * C * 4 + 4 * c0]);
        const float4 r1 = *reinterpret_cast<const float4*>(&h_res[(size_t)n * C * 4 + 4 * c0 + 4]);
        v0 += 0.25f * (r0.x + r0.y + r0.z + r0.w);
        v1 += 0.25f * (r1.x + r1.y + r1.z + r1.w);
    }
    *reinterpret_cast<float2*>(&out[(size_t)n * C + c0]) = make_float2(v0, v1);
    if (out16) {
        ushort2 o = {f2bf(v0), f2bf(v1)};
        *reinterpret_cast<ushort2*>(&out16[(size_t)n * C + c0]) = o;
    }
    if (out2_16) {
        ushort2 o = {f2bf(v0), f2bf(v1)};
        *reinterpret_cast<ushort2*>(&out2_16[(size_t)n * out2_stride + c0]) = o;
    }
}

// ---------------------------------------------------------------------------
// Temporal self-attention over T=2 states. qkv16:[2N,384] bf16 -> om16 bf16
// ---------------------------------------------------------------------------
__global__ __launch_bounds__(128) void temporal_attn(
    const unsigned short* __restrict__ qkv16, unsigned short* __restrict__ om16) {
    __shared__ float sh[768];
    int n = blockIdx.x;
    int c = threadIdx.x;
    for (int i = c; i < 768; i += 128) {
        int t = i / 384;
        sh[i] = bf2f(qkv16[(size_t)(n * 2 + t) * 384 + (i - t * 384)]);
    }
    __syncthreads();
    int head = c >> 5;
    int hb = head * 32;
    const float scale = 0.17677669529663687f;
    float o[2];
#pragma unroll
    for (int qt = 0; qt < 2; qt++) {
        float s0 = 0.f, s1 = 0.f;
#pragma unroll
        for (int d = 0; d < 32; d++) {
            float qv = sh[qt * 384 + hb + d];
            s0 = fmaf(qv, sh[0 * 384 + 128 + hb + d], s0);
            s1 = fmaf(qv, sh[1 * 384 + 128 + hb + d], s1);
        }
        s0 *= scale; s1 *= scale;
        float m = fmaxf(s0, s1);
        float p0 = expf(s0 - m), p1 = expf(s1 - m);
        float inv = 1.0f / (p0 + p1);
        o[qt] = p0 * inv * sh[0 * 384 + 256 + c] + p1 * inv * sh[1 * 384 + 256 + c];
    }
    om16[(size_t)n * 128 + c] = f2bf(0.5f * (o[0] + o[1]));
}

// ---------------------------------------------------------------------------

extern "C" void kernel_launch(void* const* d_in, const int* in_sizes, int n_in,
                              void* d_out, int out_size, void* d_ws, size_t ws_size,
                              hipStream_t stream) {
    const float* x   = (const float*)d_in[0];
    const int*   ei  = (const int*)d_in[1];
    const float* Wp  = (const float*)d_in[2];
    const float* bp  = (const float*)d_in[3];
    const float* W0  = (const float*)d_in[4];
    const float* as0 = (const float*)d_in[5];
    const float* ad0 = (const float*)d_in[6];
    const float* b0  = (const float*)d_in[7];
    const float* W1  = (const float*)d_in[8];
    const float* as1 = (const float*)d_in[9];
    const float* ad1 = (const float*)d_in[10];
    const float* b1  = (const float*)d_in[11];
    const float* W2  = (const float*)d_in[12];
    const float* as2 = (const float*)d_in[13];
    const float* ad2 = (const float*)d_in[14];
    const float* b2  = (const float*)d_in[15];
    const float* g0  = (const float*)d_in[16];
    const float* be0 = (const float*)d_in[17];
    const float* g1  = (const float*)d_in[18];
    const float* be1 = (const float*)d_in[19];
    const float* g2  = (const float*)d_in[20];
    const float* be2 = (const float*)d_in[21];
    const float* Wqkv = (const float*)d_in[22];
    const float* bqkv = (const float*)d_in[23];
    const float* Wo  = (const float*)d_in[24];
    const float* bo  = (const float*)d_in[25];
    float* out = (float*)d_out;

    const int N = N_NODES;
    float* f = (float*)d_ws;
    const size_t NH = (size_t)N * 512;
    // fp32 buffers (residual/state chain)
    float* hA  = f;                 // [N,512]
    float* hB  = hA + NH;           // [N,512]
    float* als = hB + NH;           // [N,4]
    float* ald = als + (size_t)N * 4;
    // int buffers
    int* row_start  = (int*)(ald + (size_t)N * 4);
    int* cursor     = row_start + (N + 1);
    int* sorted_id  = cursor + N;
    int* sorted_src = sorted_id + ETOT;
    int* bsum       = sorted_src + ETOT;          // NBLK_SCAN
    // bf16 buffers
    unsigned short* x16   = (unsigned short*)(bsum + NBLK_SCAN + 1);
    unsigned short* h16n  = x16 + (size_t)NPAD * 128;         // [NPAD,128]
    unsigned short* h16w  = h16n + (size_t)NPAD * 128;        // [NPAD,512]
    unsigned short* xp16  = h16w + (size_t)NPAD * 512;        // [NPAD,512]
    unsigned short* st16  = xp16 + (size_t)NPAD * 512;        // [NPAD2,128]
    unsigned short* qkv16 = st16 + (size_t)NPAD2 * 128;       // [NPAD2,384]
    unsigned short* om16  = qkv16 + (size_t)NPAD2 * 384;      // [NPAD,128]
    unsigned short* w16   = om16 + (size_t)NPAD * 128;
    unsigned short* Wp16   = w16;
    unsigned short* W016   = Wp16 + 128 * 128;
    unsigned short* W116   = W016 + 512 * 128;
    unsigned short* W216   = W116 + 512 * 512;
    unsigned short* Wqkv16 = W216 + 128 * 512;
    unsigned short* Wo16   = Wqkv16 + 384 * 128;

    // ---- zero pad rows of GEMM A-operand mirrors ----
    zero_pads<<<192, 256, 0, stream>>>(x16, h16n, h16w, st16, om16);

    // ---- weight conversions ----
    conv_bf16<<<(128 * 128 + 255) / 256, 256, 0, stream>>>(Wp, Wp16, 128 * 128);
    conv_bf16<<<(512 * 128 + 255) / 256, 256, 0, stream>>>(W0, W016, 512 * 128);
    conv_bf16<<<(512 * 512 + 255) / 256, 256, 0, stream>>>(W1, W116, 512 * 512);
    conv_bf16<<<(128 * 512 + 255) / 256, 256, 0, stream>>>(W2, W216, 128 * 512);
    conv_bf16<<<(384 * 128 + 255) / 256, 256, 0, stream>>>(Wqkv, Wqkv16, 384 * 128);
    conv_bf16<<<(128 * 128 + 255) / 256, 256, 0, stream>>>(Wo, Wo16, 128 * 128);
    conv_bf16<<<(N * 128 + 255) / 256, 256, 0, stream>>>(x, x16, N * 128);

    // ---- edge preprocessing (deterministic counting sort by dst) ----
    hipMemsetAsync(cursor, 0, N * sizeof(int), stream);
    hist_kernel<<<1024, 256, 0, stream>>>(ei, cursor);
    scanA<<<NBLK_SCAN, 256, 0, stream>>>(cursor, row_start + 1, bsum);
    scanB<<<1, 64, 0, stream>>>(bsum, row_start);
    scanC<<<NBLK_SCAN, 256, 0, stream>>>(cursor, row_start, bsum);
    scatter_kernel<<<1024, 256, 0, stream>>>(ei, cursor, sorted_id);
    segsort_kernel<<<(N + 255) / 256, 256, 0, stream>>>(ei, row_start, sorted_id,
                                                        sorted_src);

    const int GX = NPAD / 128;  // 157
    // ---- input projection -> h16n (bf16 only; fp32 C never read) ----
    {
        dim3 g(GX, 1);
        gemm_mfma<<<g, 256, 0, stream>>>(x16, Wp16, bp, nullptr, h16n, N, 128, 128,
                                         nullptr, nullptr, nullptr, nullptr, 0);
    }

    float* cur = hA;
    float* nxt = hB;
    for (int t = 0; t < 2; t++) {
        // layer 0: 128 -> 512 (4 heads)
        {
            dim3 g(GX, 4);
            gemm_mfma<<<g, 256, 0, stream>>>(h16n, W016, nullptr, nullptr, xp16,
                                             N, 128, 512, as0, ad0, als, ald, 4);
            gat_aggregate<512, 4, 0><<<N, 256, 0, stream>>>(
                xp16, als, ald, row_start, sorted_src, b0, g0, be0, nullptr, nxt,
                h16w, nullptr, 0);
            float* tmp = cur; cur = nxt; nxt = tmp;
        }
        // layer 1: 512 -> 512 (4 heads), residual
        {
            dim3 g(GX, 4);
            gemm_mfma<<<g, 256, 0, stream>>>(h16w, W116, nullptr, nullptr, xp16,
                                             N, 512, 512, as1, ad1, als, ald, 4);
            gat_aggregate<512, 4, 1><<<N, 256, 0, stream>>>(
                xp16, als, ald, row_start, sorted_src, b1, g1, be1, cur, nxt,
                h16w, nullptr, 0);
            float* tmp = cur; cur = nxt; nxt = tmp;
        }
        // layer 2: 512 -> 128 (1 head), pooled residual
        {
            dim3 g(GX, 1);
            gemm_mfma<<<g, 256, 0, stream>>>(h16w, W216, nullptr, nullptr, xp16,
                                             N, 512, 128, as2, ad2, als, ald, 1);
            gat_aggregate<128, 1, 2><<<N, 64, 0, stream>>>(
                xp16, als, ald, row_start, sorted_src, b2, g2, be2, cur, nxt,
                h16n, st16 + (size_t)t * 128, 256);
            float* tmp = cur; cur = nxt; nxt = tmp;
        }
    }

    // ---- temporal attention ----
    {
        dim3 g(NPAD2 / 128, 3);
        gemm_mfma<<<g, 256, 0, stream>>>(st16, Wqkv16, bqkv, nullptr, qkv16,
                                         2 * N, 128, 384, nullptr, nullptr,
                                         nullptr, nullptr, 0);
    }
    temporal_attn<<<N, 128, 0, stream>>>(qkv16, om16);
    {
        dim3 g(GX, 1);
        gemm_mfma<<<g, 256, 0, stream>>>(om16, Wo16, bo, out, nullptr,
                                         N, 128, 128, nullptr, nullptr,
                                         nullptr, nullptr, 0);
    }
}

// Round 9
// 735.394 us; speedup vs baseline: 1.6489x; 1.0860x over previous
//
#include <hip/hip_runtime.h>
#include <math.h>

#define N_NODES 20000
#define N_EDGES 256000
#define ETOT (N_EDGES + N_NODES)
#define NPAD 20096    // 157*128
#define NPAD2 40064   // 313*128 (2N rows padded)
#define NBLK_SCAN ((N_NODES + 255) / 256)   // 79

typedef __attribute__((ext_vector_type(8))) short bf16x8;
typedef __attribute__((ext_vector_type(4))) float f32x4;

__device__ __forceinline__ unsigned short f2bf(float f) {
    unsigned int u = __builtin_bit_cast(unsigned int, f);
    u = (u + 0x7fff + ((u >> 16) & 1)) >> 16;
    return (unsigned short)u;
}

__device__ __forceinline__ float bf2f(unsigned short u) {
    return __builtin_bit_cast(float, (unsigned int)u << 16);
}

__device__ __forceinline__ void gload_lds16(const void* g, void* l) {
    __builtin_amdgcn_global_load_lds(
        (const __attribute__((address_space(1))) void*)g,
        (__attribute__((address_space(3))) void*)l, 16, 0, 0);
}

// ---------------------------------------------------------------------------
// Edge preprocessing: counting sort by dst, deterministic order within segment
// ---------------------------------------------------------------------------

__global__ void hist_kernel(const int* __restrict__ ei, int* __restrict__ cnt) {
    for (int e = blockIdx.x * blockDim.x + threadIdx.x; e < ETOT;
         e += gridDim.x * blockDim.x) {
        int d = (e < N_EDGES) ? ei[N_EDGES + e] : (e - N_EDGES);
        atomicAdd(&cnt[d], 1);
    }
}

__global__ __launch_bounds__(256) void scanA(const int* __restrict__ cnt,
                                             int* __restrict__ incl,
                                             int* __restrict__ bsum) {
    __shared__ int sh[256];
    int t = threadIdx.x;
    int i = blockIdx.x * 256 + t;
    int v = (i < N_NODES) ? cnt[i] : 0;
    sh[t] = v;
    __syncthreads();
#pragma unroll
    for (int off = 1; off < 256; off <<= 1) {
        int u = (t >= off) ? sh[t - off] : 0;
        __syncthreads();
        sh[t] += u;
        __syncthreads();
    }
    if (i < N_NODES) incl[i] = sh[t];
    if (t == 255) bsum[blockIdx.x] = sh[255];
}

__global__ void scanB(int* __restrict__ bsum, int* __restrict__ row_start) {
    if (threadIdx.x == 0) {
        int s = 0;
        for (int i = 0; i < NBLK_SCAN; i++) { int v = bsum[i]; bsum[i] = s; s += v; }
        row_start[0] = 0;
    }
}

__global__ __launch_bounds__(256) void scanC(int* __restrict__ cursor,
                                             int* __restrict__ row_start,
                                             const int* __restrict__ bsum) {
    int i = blockIdx.x * 256 + threadIdx.x;
    if (i < N_NODES) {
        int incl = row_start[i + 1] + bsum[blockIdx.x];
        row_start[i + 1] = incl;
        cursor[i] = incl - cursor[i];
    }
}

__global__ void scatter_kernel(const int* __restrict__ ei, int* __restrict__ cursor,
                               int* __restrict__ sorted_id) {
    for (int e = blockIdx.x * blockDim.x + threadIdx.x; e < ETOT;
         e += gridDim.x * blockDim.x) {
        int d = (e < N_EDGES) ? ei[N_EDGES + e] : (e - N_EDGES);
        int pos = atomicAdd(&cursor[d], 1);
        sorted_id[pos] = e;
    }
}

__global__ void segsort_kernel(const int* __restrict__ ei,
                               const int* __restrict__ row_start,
                               int* __restrict__ sorted_id,
                               int* __restrict__ sorted_src) {
    int n = blockIdx.x * blockDim.x + threadIdx.x;
    if (n >= N_NODES) return;
    int s = row_start[n], e = row_start[n + 1];
    for (int i = s + 1; i < e; i++) {
        int v = sorted_id[i];
        int j = i - 1;
        while (j >= s && sorted_id[j] > v) { sorted_id[j + 1] = sorted_id[j]; j--; }
        sorted_id[j + 1] = v;
    }
    for (int i = s; i < e; i++) {
        int id = sorted_id[i];
        sorted_src[i] = (id < N_EDGES) ? ei[id] : (id - N_EDGES);
    }
}

// ---------------------------------------------------------------------------
// bf16 conversion + pad-row zeroing
// ---------------------------------------------------------------------------
__global__ void conv_bf16(const float* __restrict__ src,
                          unsigned short* __restrict__ dst, int n) {
    int i = blockIdx.x * blockDim.x + threadIdx.x;
    if (i < n) dst[i] = f2bf(src[i]);
}

__global__ void zero_pads(unsigned short* x16, unsigned short* h16n,
                          unsigned short* h16w, unsigned short* st16,
                          unsigned short* om16) {
    int i = blockIdx.x * blockDim.x + threadIdx.x;
    const int PR = NPAD - N_NODES;  // 96 pad rows
    if (i < PR * 128) {
        x16[(size_t)N_NODES * 128 + i] = 0;
        h16n[(size_t)N_NODES * 128 + i] = 0;
        om16[(size_t)N_NODES * 128 + i] = 0;
    }
    if (i < PR * 512) h16w[(size_t)N_NODES * 512 + i] = 0;
    if (i < (NPAD2 - 2 * N_NODES) * 128) st16[(size_t)(2 * N_NODES) * 128 + i] = 0;
}

// ---------------------------------------------------------------------------
// bf16 MFMA GEMM (optional fused GAT attention-coefficient epilogue)
// ---------------------------------------------------------------------------
__global__ __launch_bounds__(256) void gemm_mfma(
    const unsigned short* __restrict__ A, const unsigned short* __restrict__ B,
    const float* __restrict__ bias, float* __restrict__ Cf,
    unsigned short* __restrict__ C16, int R, int K, int ldc,
    const float* __restrict__ a_s, const float* __restrict__ a_d,
    float* __restrict__ al_s, float* __restrict__ al_d, int H) {
    __shared__ unsigned short Al[128 * 64];
    __shared__ unsigned short Bl[128 * 64];
    __shared__ float red_s[4][64], red_d[4][64];
    int tid = threadIdx.x;
    int lane = tid & 63, wv = tid >> 6;
    int wr = (wv >> 1) * 64, wc = (wv & 1) * 64;
    size_t br = (size_t)blockIdx.x * 128;
    size_t bc = (size_t)blockIdx.y * 128;
    f32x4 acc[4][4] = {};
    for (int k0 = 0; k0 < K; k0 += 64) {
#pragma unroll
        for (int i = 0; i < 4; i++) {
            int idx = i * 256 + tid;
            int row = idx >> 3;
            int kb = (idx & 7) << 4;
            gload_lds16((const char*)(A + (br + row) * K + k0) + kb,
                        (char*)Al + idx * 16);
            gload_lds16((const char*)(B + (bc + row) * K + k0) + kb,
                        (char*)Bl + idx * 16);
        }
        __syncthreads();
#pragma unroll
        for (int kk = 0; kk < 2; kk++) {
            bf16x8 af[4], bfr[4];
#pragma unroll
            for (int m = 0; m < 4; m++)
                af[m] = *(const bf16x8*)&Al[(wr + m * 16 + (lane & 15)) * 64 +
                                            kk * 32 + (lane >> 4) * 8];
#pragma unroll
            for (int n = 0; n < 4; n++)
                bfr[n] = *(const bf16x8*)&Bl[(wc + n * 16 + (lane & 15)) * 64 +
                                             kk * 32 + (lane >> 4) * 8];
#pragma unroll
            for (int m = 0; m < 4; m++)
#pragma unroll
                for (int n = 0; n < 4; n++)
                    acc[m][n] = __builtin_amdgcn_mfma_f32_16x16x32_bf16(
                        af[m], bfr[n], acc[m][n], 0, 0, 0);
        }
        __syncthreads();
    }

    if (al_s) {
        float asr[4], adr[4];
#pragma unroll
        for (int n = 0; n < 4; n++) {
            int c = (int)bc + wc + n * 16 + (lane & 15);
            asr[n] = a_s[c];
            adr[n] = a_d[c];
        }
        float ps[4][4], pd[4][4];
#pragma unroll
        for (int m = 0; m < 4; m++)
#pragma unroll
            for (int j = 0; j < 4; j++) {
                float s = 0.f, d = 0.f;
#pragma unroll
                for (int n = 0; n < 4; n++) {
                    float v = acc[m][n][j];
                    s = fmaf(v, asr[n], s);
                    d = fmaf(v, adr[n], d);
                }
#pragma unroll
                for (int off = 8; off; off >>= 1) {
                    s += __shfl_xor(s, off);
                    d += __shfl_xor(d, off);
                }
                ps[m][j] = s;
                pd[m][j] = d;
            }
        if ((lane & 15) == 0) {
#pragma unroll
            for (int m = 0; m < 4; m++)
#pragma unroll
                for (int j = 0; j < 4; j++) {
                    int lr = m * 16 + (lane >> 4) * 4 + j;
                    red_s[wv][lr] = ps[m][j];
                    red_d[wv][lr] = pd[m][j];
                }
        }
        __syncthreads();
        if (tid < 128) {
            int half = tid >> 6, lr = tid & 63;
            float s = red_s[half * 2][lr] + red_s[half * 2 + 1][lr];
            float d = red_d[half * 2][lr] + red_d[half * 2 + 1][lr];
            size_t r = br + tid;
            if (r < (size_t)R) {
                al_s[r * H + blockIdx.y] = s;
                al_d[r * H + blockIdx.y] = d;
            }
        }
    }

#pragma unroll
    for (int m = 0; m < 4; m++) {
        int r0 = wr + m * 16 + (lane >> 4) * 4;
#pragma unroll
        for (int n = 0; n < 4; n++) {
            int c = (int)bc + wc + n * 16 + (lane & 15);
            float bv = bias ? bias[c] : 0.f;
#pragma unroll
            for (int j = 0; j < 4; j++) {
                size_t r = br + r0 + j;
                if (r < (size_t)R) {
                    float v = acc[m][n][j] + bv;
                    if (Cf) Cf[r * ldc + c] = v;
                    if (C16) C16[r * ldc + c] = f2bf(v);
                }
            }
        }
    }
}

// ---------------------------------------------------------------------------
// Fused GAT aggregation + bias + ELU + LayerNorm + residual.
// Fast path (deg<=64): single-pass in-register segment softmax, one barrier.
// Requires NW == HEADS (true for both instantiations: 512/4 and 128/1).
// ---------------------------------------------------------------------------
template <int C, int HEADS, int RES>
__global__ __launch_bounds__(C / 2) void gat_aggregate(
    const unsigned short* __restrict__ xp16, const float* __restrict__ al_s,
    const float* __restrict__ al_d, const int* __restrict__ row_start,
    const int* __restrict__ srcs, const float* __restrict__ bias,
    const float* __restrict__ gamma, const float* __restrict__ beta,
    const float* __restrict__ h_res, float* __restrict__ out,
    unsigned short* __restrict__ out16, unsigned short* __restrict__ out2_16,
    int out2_stride) {
    const int BLK = C / 2;
    const int NW = BLK / 64;
    int n = blockIdx.x;
    int tid = threadIdx.x;
    int lane = tid & 63, wv = tid >> 6;
    __shared__ int src_sh[64];
    __shared__ float w_sh[64 * HEADS];
    __shared__ float red_sh[2 * NW];
    __shared__ float m_sh[HEADS], s_sh[HEADS];
    int base = row_start[n];
    int deg = row_start[n + 1] - base;

    float acc0 = 0.f, acc1 = 0.f;
    const int c0 = 2 * tid;
    const int h = (HEADS == 1) ? 0 : (c0 >> 7);  // wave-uniform

    if (deg <= 64) {
        // ---- single-pass softmax: wave wv owns head wv; lane e owns edge e ----
        int src = 0;
        float v = -3.4e38f;
        if (lane < deg) {
            src = srcs[base + lane];
            if (wv == 0) src_sh[lane] = src;
            float t = al_s[src * HEADS + wv] + al_d[n * HEADS + wv];
            v = t > 0.f ? t : 0.2f * t;
        }
        float m = v;
#pragma unroll
        for (int off = 32; off; off >>= 1) m = fmaxf(m, __shfl_xor(m, off));
        float p = expf(v - m);  // inactive lanes: exp(-huge)=0
        float s = p;
#pragma unroll
        for (int off = 32; off; off >>= 1) s += __shfl_xor(s, off);
        s += 1e-16f;
        if (lane < deg) w_sh[lane * HEADS + wv] = p / s;
        __syncthreads();
        // ---- gather ----
        const unsigned short* xb = xp16 + c0;
#pragma unroll 4
        for (int j = 0; j < deg; j++) {
            const ushort2 vv =
                *reinterpret_cast<const ushort2*>(&xb[(size_t)src_sh[j] * C]);
            float w = w_sh[j * HEADS + h];
            acc0 = fmaf(w, bf2f(vv.x), acc0);
            acc1 = fmaf(w, bf2f(vv.y), acc1);
        }
    } else {
        // ---- generic path (rare): 2-pass stats + chunked gather ----
        for (int hh = wv; hh < HEADS; hh += NW) {
            float ald = al_d[n * HEADS + hh];
            float m = -3.4e38f;
            for (int e = lane; e < deg; e += 64) {
                float v = al_s[srcs[base + e] * HEADS + hh] + ald;
                v = v > 0.f ? v : 0.2f * v;
                m = fmaxf(m, v);
            }
#pragma unroll
            for (int off = 32; off; off >>= 1) m = fmaxf(m, __shfl_xor(m, off));
            float s = 0.f;
            for (int e = lane; e < deg; e += 64) {
                float v = al_s[srcs[base + e] * HEADS + hh] + ald;
                v = v > 0.f ? v : 0.2f * v;
                s += expf(v - m);
            }
#pragma unroll
            for (int off = 32; off; off >>= 1) s += __shfl_xor(s, off);
            if (lane == 0) { m_sh[hh] = m; s_sh[hh] = s + 1e-16f; }
        }
        __syncthreads();
        for (int cb = 0; cb < deg; cb += 64) {
            int clen = min(64, deg - cb);
            if (tid < clen) src_sh[tid] = srcs[base + cb + tid];
            __syncthreads();
            if (tid < clen * HEADS) {
                int e = tid / HEADS, hh = tid % HEADS;
                int sidx = src_sh[e];
                float v = al_s[sidx * HEADS + hh] + al_d[n * HEADS + hh];
                v = v > 0.f ? v : 0.2f * v;
                w_sh[tid] = expf(v - m_sh[hh]) / s_sh[hh];
            }
            __syncthreads();
            for (int j = 0; j < clen; j++) {
                const ushort2 vv = *reinterpret_cast<const ushort2*>(
                    &xp16[(size_t)src_sh[j] * C + c0]);
                float w = w_sh[j * HEADS + h];
                acc0 = fmaf(w, bf2f(vv.x), acc0);
                acc1 = fmaf(w, bf2f(vv.y), acc1);
            }
            __syncthreads();
        }
    }

    // ---- epilogue: +bias, ELU, LayerNorm, residual ----
    float2 bv = *reinterpret_cast<const float2*>(&bias[c0]);
    float v0 = acc0 + bv.x;
    float v1 = acc1 + bv.y;
    v0 = v0 > 0.f ? v0 : expm1f(v0);
    v1 = v1 > 0.f ? v1 : expm1f(v1);
    float s = v0 + v1, q = v0 * v0 + v1 * v1;
#pragma unroll
    for (int off = 32; off; off >>= 1) {
        s += __shfl_xor(s, off);
        q += __shfl_xor(q, off);
    }
    if (NW > 1) {
        __syncthreads();
        if (lane == 0) { red_sh[wv * 2] = s; red_sh[wv * 2 + 1] = q; }
        __syncthreads();
        s = 0.f; q = 0.f;
#pragma unroll
        for (int w = 0; w < NW; w++) { s += red_sh[w * 2]; q += red_sh[w * 2 + 1]; }
    }
    float mu = s / C;
    float var = q / C - mu * mu;
    float rstd = 1.0f / sqrtf(var + 1e-5f);
    float2 gv = *reinterpret_cast<const float2*>(&gamma[c0]);
    float2 bev = *reinterpret_cast<const float2*>(&beta[c0]);
    v0 = (v0 - mu) * rstd * gv.x + bev.x;
    v1 = (v1 - mu) * rstd * gv.y + bev.y;
    if (RES == 1) {
        float2 rv = *reinterpret_cast<const float2*>(&h_res[(size_t)n * C + c0]);
        v0 += rv.x;
        v1 += rv.y;
    } else if (RES == 2) {
        const float4 r0 = *reinterpret_cast<const float4*>(&h_res[(size_t)n * C * 4 + 4 * c0]);
        const float4 r1 = *reinterpret_cast<const float4*>(&h_res[(size_t)n * C * 4 + 4 * c0 + 4]);
        v0 += 0.25f * (r0.x + r0.y + r0.z + r0.w);
        v1 += 0.25f * (r1.x + r1.y + r1.z + r1.w);
    }
    *reinterpret_cast<float2*>(&out[(size_t)n * C + c0]) = make_float2(v0, v1);
    if (out16) {
        ushort2 o = {f2bf(v0), f2bf(v1)};
        *reinterpret_cast<ushort2*>(&out16[(size_t)n * C + c0]) = o;
    }
    if (out2_16) {
        ushort2 o = {f2bf(v0), f2bf(v1)};
        *reinterpret_cast<ushort2*>(&out2_16[(size_t)n * out2_stride + c0]) = o;
    }
}

// ---------------------------------------------------------------------------
// Temporal self-attention over T=2 states. qkv16:[2N,384] bf16 -> om16 bf16
// ---------------------------------------------------------------------------
__global__ __launch_bounds__(128) void temporal_attn(
    const unsigned short* __restrict__ qkv16, unsigned short* __restrict__ om16) {
    __shared__ float sh[768];
    int n = blockIdx.x;
    int c = threadIdx.x;
    for (int i = c; i < 768; i += 128) {
        int t = i / 384;
        sh[i] = bf2f(qkv16[(size_t)(n * 2 + t) * 384 + (i - t * 384)]);
    }
    __syncthreads();
    int head = c >> 5;
    int hb = head * 32;
    const float scale = 0.17677669529663687f;
    float o[2];
#pragma unroll
    for (int qt = 0; qt < 2; qt++) {
        float s0 = 0.f, s1 = 0.f;
#pragma unroll
        for (int d = 0; d < 32; d++) {
            float qv = sh[qt * 384 + hb + d];
            s0 = fmaf(qv, sh[0 * 384 + 128 + hb + d], s0);
            s1 = fmaf(qv, sh[1 * 384 + 128 + hb + d], s1);
        }
        s0 *= scale; s1 *= scale;
        float m = fmaxf(s0, s1);
        float p0 = expf(s0 - m), p1 = expf(s1 - m);
        float inv = 1.0f / (p0 + p1);
        o[qt] = p0 * inv * sh[0 * 384 + 256 + c] + p1 * inv * sh[1 * 384 + 256 + c];
    }
    om16[(size_t)n * 128 + c] = f2bf(0.5f * (o[0] + o[1]));
}

// ---------------------------------------------------------------------------

extern "C" void kernel_launch(void* const* d_in, const int* in_sizes, int n_in,
                              void* d_out, int out_size, void* d_ws, size_t ws_size,
                              hipStream_t stream) {
    const float* x   = (const float*)d_in[0];
    const int*   ei  = (const int*)d_in[1];
    const float* Wp  = (const float*)d_in[2];
    const float* bp  = (const float*)d_in[3];
    const float* W0  = (const float*)d_in[4];
    const float* as0 = (const float*)d_in[5];
    const float* ad0 = (const float*)d_in[6];
    const float* b0  = (const float*)d_in[7];
    const float* W1  = (const float*)d_in[8];
    const float* as1 = (const float*)d_in[9];
    const float* ad1 = (const float*)d_in[10];
    const float* b1  = (const float*)d_in[11];
    const float* W2  = (const float*)d_in[12];
    const float* as2 = (const float*)d_in[13];
    const float* ad2 = (const float*)d_in[14];
    const float* b2  = (const float*)d_in[15];
    const float* g0  = (const float*)d_in[16];
    const float* be0 = (const float*)d_in[17];
    const float* g1  = (const float*)d_in[18];
    const float* be1 = (const float*)d_in[19];
    const float* g2  = (const float*)d_in[20];
    const float* be2 = (const float*)d_in[21];
    const float* Wqkv = (const float*)d_in[22];
    const float* bqkv = (const float*)d_in[23];
    const float* Wo  = (const float*)d_in[24];
    const float* bo  = (const float*)d_in[25];
    float* out = (float*)d_out;

    const int N = N_NODES;
    float* f = (float*)d_ws;
    const size_t NH = (size_t)N * 512;
    // fp32 buffers (residual/state chain)
    float* hA  = f;                 // [N,512]
    float* hB  = hA + NH;           // [N,512]
    float* als = hB + NH;           // [N,4]
    float* ald = als + (size_t)N * 4;
    // int buffers
    int* row_start  = (int*)(ald + (size_t)N * 4);
    int* cursor     = row_start + (N + 1);
    int* sorted_id  = cursor + N;
    int* sorted_src = sorted_id + ETOT;
    int* bsum       = sorted_src + ETOT;          // NBLK_SCAN
    // bf16 buffers
    unsigned short* x16   = (unsigned short*)(bsum + NBLK_SCAN + 1);
    unsigned short* h16n  = x16 + (size_t)NPAD * 128;         // [NPAD,128]
    unsigned short* h16w  = h16n + (size_t)NPAD * 128;        // [NPAD,512]
    unsigned short* xp16  = h16w + (size_t)NPAD * 512;        // [NPAD,512]
    unsigned short* st16  = xp16 + (size_t)NPAD * 512;        // [NPAD2,128]
    unsigned short* qkv16 = st16 + (size_t)NPAD2 * 128;       // [NPAD2,384]
    unsigned short* om16  = qkv16 + (size_t)NPAD2 * 384;      // [NPAD,128]
    unsigned short* w16   = om16 + (size_t)NPAD * 128;
    unsigned short* Wp16   = w16;
    unsigned short* W016   = Wp16 + 128 * 128;
    unsigned short* W116   = W016 + 512 * 128;
    unsigned short* W216   = W116 + 512 * 512;
    unsigned short* Wqkv16 = W216 + 128 * 512;
    unsigned short* Wo16   = Wqkv16 + 384 * 128;

    // ---- zero pad rows of GEMM A-operand mirrors ----
    zero_pads<<<192, 256, 0, stream>>>(x16, h16n, h16w, st16, om16);

    // ---- weight conversions ----
    conv_bf16<<<(128 * 128 + 255) / 256, 256, 0, stream>>>(Wp, Wp16, 128 * 128);
    conv_bf16<<<(512 * 128 + 255) / 256, 256, 0, stream>>>(W0, W016, 512 * 128);
    conv_bf16<<<(512 * 512 + 255) / 256, 256, 0, stream>>>(W1, W116, 512 * 512);
    conv_bf16<<<(128 * 512 + 255) / 256, 256, 0, stream>>>(W2, W216, 128 * 512);
    conv_bf16<<<(384 * 128 + 255) / 256, 256, 0, stream>>>(Wqkv, Wqkv16, 384 * 128);
    conv_bf16<<<(128 * 128 + 255) / 256, 256, 0, stream>>>(Wo, Wo16, 128 * 128);
    conv_bf16<<<(N * 128 + 255) / 256, 256, 0, stream>>>(x, x16, N * 128);

    // ---- edge preprocessing (deterministic counting sort by dst) ----
    hipMemsetAsync(cursor, 0, N * sizeof(int), stream);
    hist_kernel<<<1024, 256, 0, stream>>>(ei, cursor);
    scanA<<<NBLK_SCAN, 256, 0, stream>>>(cursor, row_start + 1, bsum);
    scanB<<<1, 64, 0, stream>>>(bsum, row_start);
    scanC<<<NBLK_SCAN, 256, 0, stream>>>(cursor, row_start, bsum);
    scatter_kernel<<<1024, 256, 0, stream>>>(ei, cursor, sorted_id);
    segsort_kernel<<<(N + 255) / 256, 256, 0, stream>>>(ei, row_start, sorted_id,
                                                        sorted_src);

    const int GX = NPAD / 128;  // 157
    // ---- input projection -> h16n ----
    {
        dim3 g(GX, 1);
        gemm_mfma<<<g, 256, 0, stream>>>(x16, Wp16, bp, nullptr, h16n, N, 128, 128,
                                         nullptr, nullptr, nullptr, nullptr, 0);
    }

    float* cur = hA;
    float* nxt = hB;
    for (int t = 0; t < 2; t++) {
        // layer 0: 128 -> 512 (4 heads)
        {
            dim3 g(GX, 4);
            gemm_mfma<<<g, 256, 0, stream>>>(h16n, W016, nullptr, nullptr, xp16,
                                             N, 128, 512, as0, ad0, als, ald, 4);
            gat_aggregate<512, 4, 0><<<N, 256, 0, stream>>>(
                xp16, als, ald, row_start, sorted_src, b0, g0, be0, nullptr, nxt,
                h16w, nullptr, 0);
            float* tmp = cur; cur = nxt; nxt = tmp;
        }
        // layer 1: 512 -> 512 (4 heads), residual
        {
            dim3 g(GX, 4);
            gemm_mfma<<<g, 256, 0, stream>>>(h16w, W116, nullptr, nullptr, xp16,
                                             N, 512, 512, as1, ad1, als, ald, 4);
            gat_aggregate<512, 4, 1><<<N, 256, 0, stream>>>(
                xp16, als, ald, row_start, sorted_src, b1, g1, be1, cur, nxt,
                h16w, nullptr, 0);
            float* tmp = cur; cur = nxt; nxt = tmp;
        }
        // layer 2: 512 -> 128 (1 head), pooled residual
        {
            dim3 g(GX, 1);
            gemm_mfma<<<g, 256, 0, stream>>>(h16w, W216, nullptr, nullptr, xp16,
                                             N, 512, 128, as2, ad2, als, ald, 1);
            gat_aggregate<128, 1, 2><<<N, 64, 0, stream>>>(
                xp16, als, ald, row_start, sorted_src, b2, g2, be2, cur, nxt,
                h16n, st16 + (size_t)t * 128, 256);
            float* tmp = cur; cur = nxt; nxt = tmp;
        }
    }

    // ---- temporal attention ----
    {
        dim3 g(NPAD2 / 128, 3);
        gemm_mfma<<<g, 256, 0, stream>>>(st16, Wqkv16, bqkv, nullptr, qkv16,
                                         2 * N, 128, 384, nullptr, nullptr,
                                         nullptr, nullptr, 0);
    }
    temporal_attn<<<N, 128, 0, stream>>>(qkv16, om16);
    {
        dim3 g(GX, 1);
        gemm_mfma<<<g, 256, 0, stream>>>(om16, Wo16, bo, out, nullptr,
                                         N, 128, 128, nullptr, nullptr,
                                         nullptr, nullptr, 0);
    }
}

// Round 11
// 711.650 us; speedup vs baseline: 1.7039x; 1.0334x over previous
//
#include <hip/hip_runtime.h>
#include <math.h>

#define N_NODES 20000
#define N_EDGES 256000
#define ETOT (N_EDGES + N_NODES)
#define NPAD 20096    // 157*128
#define NPAD2 40064   // 313*128 (2N rows padded)
#define NBLK_SCAN ((N_NODES + 255) / 256)   // 79

typedef __attribute__((ext_vector_type(8))) short bf16x8;
typedef __attribute__((ext_vector_type(4))) float f32x4;

__device__ __forceinline__ unsigned short f2bf(float f) {
    unsigned int u = __builtin_bit_cast(unsigned int, f);
    u = (u + 0x7fff + ((u >> 16) & 1)) >> 16;
    return (unsigned short)u;
}

__device__ __forceinline__ float bf2f(unsigned short u) {
    return __builtin_bit_cast(float, (unsigned int)u << 16);
}

__device__ __forceinline__ void gload_lds16(const void* g, void* l) {
    __builtin_amdgcn_global_load_lds(
        (const __attribute__((address_space(1))) void*)g,
        (__attribute__((address_space(3))) void*)l, 16, 0, 0);
}

// unpack uint4 (8 bf16) and fma into acc[8]
__device__ __forceinline__ void fma8(float* acc, uint4 v, float w) {
    acc[0] = fmaf(w, __builtin_bit_cast(float, v.x << 16), acc[0]);
    acc[1] = fmaf(w, __builtin_bit_cast(float, v.x & 0xffff0000u), acc[1]);
    acc[2] = fmaf(w, __builtin_bit_cast(float, v.y << 16), acc[2]);
    acc[3] = fmaf(w, __builtin_bit_cast(float, v.y & 0xffff0000u), acc[3]);
    acc[4] = fmaf(w, __builtin_bit_cast(float, v.z << 16), acc[4]);
    acc[5] = fmaf(w, __builtin_bit_cast(float, v.z & 0xffff0000u), acc[5]);
    acc[6] = fmaf(w, __builtin_bit_cast(float, v.w << 16), acc[6]);
    acc[7] = fmaf(w, __builtin_bit_cast(float, v.w & 0xffff0000u), acc[7]);
}

// ---------------------------------------------------------------------------
// Edge preprocessing: counting sort by dst, deterministic order within segment
// ---------------------------------------------------------------------------

__global__ void hist_kernel(const int* __restrict__ ei, int* __restrict__ cnt) {
    for (int e = blockIdx.x * blockDim.x + threadIdx.x; e < ETOT;
         e += gridDim.x * blockDim.x) {
        int d = (e < N_EDGES) ? ei[N_EDGES + e] : (e - N_EDGES);
        atomicAdd(&cnt[d], 1);
    }
}

__global__ __launch_bounds__(256) void scanA(const int* __restrict__ cnt,
                                             int* __restrict__ incl,
                                             int* __restrict__ bsum) {
    __shared__ int sh[256];
    int t = threadIdx.x;
    int i = blockIdx.x * 256 + t;
    int v = (i < N_NODES) ? cnt[i] : 0;
    sh[t] = v;
    __syncthreads();
#pragma unroll
    for (int off = 1; off < 256; off <<= 1) {
        int u = (t >= off) ? sh[t - off] : 0;
        __syncthreads();
        sh[t] += u;
        __syncthreads();
    }
    if (i < N_NODES) incl[i] = sh[t];
    if (t == 255) bsum[blockIdx.x] = sh[255];
}

__global__ void scanB(int* __restrict__ bsum, int* __restrict__ row_start) {
    if (threadIdx.x == 0) {
        int s = 0;
        for (int i = 0; i < NBLK_SCAN; i++) { int v = bsum[i]; bsum[i] = s; s += v; }
        row_start[0] = 0;
    }
}

__global__ __launch_bounds__(256) void scanC(int* __restrict__ cursor,
                                             int* __restrict__ row_start,
                                             const int* __restrict__ bsum) {
    int i = blockIdx.x * 256 + threadIdx.x;
    if (i < N_NODES) {
        int incl = row_start[i + 1] + bsum[blockIdx.x];
        row_start[i + 1] = incl;
        cursor[i] = incl - cursor[i];
    }
}

__global__ void scatter_kernel(const int* __restrict__ ei, int* __restrict__ cursor,
                               int* __restrict__ sorted_id) {
    for (int e = blockIdx.x * blockDim.x + threadIdx.x; e < ETOT;
         e += gridDim.x * blockDim.x) {
        int d = (e < N_EDGES) ? ei[N_EDGES + e] : (e - N_EDGES);
        int pos = atomicAdd(&cursor[d], 1);
        sorted_id[pos] = e;
    }
}

__global__ void segsort_kernel(const int* __restrict__ ei,
                               const int* __restrict__ row_start,
                               int* __restrict__ sorted_id,
                               int* __restrict__ sorted_src) {
    int n = blockIdx.x * blockDim.x + threadIdx.x;
    if (n >= N_NODES) return;
    int s = row_start[n], e = row_start[n + 1];
    for (int i = s + 1; i < e; i++) {
        int v = sorted_id[i];
        int j = i - 1;
        while (j >= s && sorted_id[j] > v) { sorted_id[j + 1] = sorted_id[j]; j--; }
        sorted_id[j + 1] = v;
    }
    for (int i = s; i < e; i++) {
        int id = sorted_id[i];
        sorted_src[i] = (id < N_EDGES) ? ei[id] : (id - N_EDGES);
    }
}

// ---------------------------------------------------------------------------
// bf16 conversion + pad-row zeroing
// ---------------------------------------------------------------------------
__global__ void conv_bf16(const float* __restrict__ src,
                          unsigned short* __restrict__ dst, int n) {
    int i = blockIdx.x * blockDim.x + threadIdx.x;
    if (i < n) dst[i] = f2bf(src[i]);
}

__global__ void zero_pads(unsigned short* x16, unsigned short* h16n,
                          unsigned short* h16w, unsigned short* st16,
                          unsigned short* om16) {
    int i = blockIdx.x * blockDim.x + threadIdx.x;
    const int PR = NPAD - N_NODES;  // 96 pad rows
    if (i < PR * 128) {
        x16[(size_t)N_NODES * 128 + i] = 0;
        h16n[(size_t)N_NODES * 128 + i] = 0;
        om16[(size_t)N_NODES * 128 + i] = 0;
    }
    if (i < PR * 512) h16w[(size_t)N_NODES * 512 + i] = 0;
    if (i < (NPAD2 - 2 * N_NODES) * 128) st16[(size_t)(2 * N_NODES) * 128 + i] = 0;
}

// ---------------------------------------------------------------------------
// bf16 MFMA GEMM (optional fused GAT attention-coefficient epilogue)
// ---------------------------------------------------------------------------
__global__ __launch_bounds__(256) void gemm_mfma(
    const unsigned short* __restrict__ A, const unsigned short* __restrict__ B,
    const float* __restrict__ bias, float* __restrict__ Cf,
    unsigned short* __restrict__ C16, int R, int K, int ldc,
    const float* __restrict__ a_s, const float* __restrict__ a_d,
    float* __restrict__ al_s, float* __restrict__ al_d, int H) {
    __shared__ unsigned short Al[128 * 64];
    __shared__ unsigned short Bl[128 * 64];
    __shared__ float red_s[4][64], red_d[4][64];
    int tid = threadIdx.x;
    int lane = tid & 63, wv = tid >> 6;
    int wr = (wv >> 1) * 64, wc = (wv & 1) * 64;
    size_t br = (size_t)blockIdx.x * 128;
    size_t bc = (size_t)blockIdx.y * 128;
    f32x4 acc[4][4] = {};
    for (int k0 = 0; k0 < K; k0 += 64) {
#pragma unroll
        for (int i = 0; i < 4; i++) {
            int idx = i * 256 + tid;
            int row = idx >> 3;
            int kb = (idx & 7) << 4;
            gload_lds16((const char*)(A + (br + row) * K + k0) + kb,
                        (char*)Al + idx * 16);
            gload_lds16((const char*)(B + (bc + row) * K + k0) + kb,
                        (char*)Bl + idx * 16);
        }
        __syncthreads();
#pragma unroll
        for (int kk = 0; kk < 2; kk++) {
            bf16x8 af[4], bfr[4];
#pragma unroll
            for (int m = 0; m < 4; m++)
                af[m] = *(const bf16x8*)&Al[(wr + m * 16 + (lane & 15)) * 64 +
                                            kk * 32 + (lane >> 4) * 8];
#pragma unroll
            for (int n = 0; n < 4; n++)
                bfr[n] = *(const bf16x8*)&Bl[(wc + n * 16 + (lane & 15)) * 64 +
                                             kk * 32 + (lane >> 4) * 8];
#pragma unroll
            for (int m = 0; m < 4; m++)
#pragma unroll
                for (int n = 0; n < 4; n++)
                    acc[m][n] = __builtin_amdgcn_mfma_f32_16x16x32_bf16(
                        af[m], bfr[n], acc[m][n], 0, 0, 0);
        }
        __syncthreads();
    }

    if (al_s) {
        float asr[4], adr[4];
#pragma unroll
        for (int n = 0; n < 4; n++) {
            int c = (int)bc + wc + n * 16 + (lane & 15);
            asr[n] = a_s[c];
            adr[n] = a_d[c];
        }
        float ps[4][4], pd[4][4];
#pragma unroll
        for (int m = 0; m < 4; m++)
#pragma unroll
            for (int j = 0; j < 4; j++) {
                float s = 0.f, d = 0.f;
#pragma unroll
                for (int n = 0; n < 4; n++) {
                    float v = acc[m][n][j];
                    s = fmaf(v, asr[n], s);
                    d = fmaf(v, adr[n], d);
                }
#pragma unroll
                for (int off = 8; off; off >>= 1) {
                    s += __shfl_xor(s, off);
                    d += __shfl_xor(d, off);
                }
                ps[m][j] = s;
                pd[m][j] = d;
            }
        if ((lane & 15) == 0) {
#pragma unroll
            for (int m = 0; m < 4; m++)
#pragma unroll
                for (int j = 0; j < 4; j++) {
                    int lr = m * 16 + (lane >> 4) * 4 + j;
                    red_s[wv][lr] = ps[m][j];
                    red_d[wv][lr] = pd[m][j];
                }
        }
        __syncthreads();
        if (tid < 128) {
            int half = tid >> 6, lr = tid & 63;
            float s = red_s[half * 2][lr] + red_s[half * 2 + 1][lr];
            float d = red_d[half * 2][lr] + red_d[half * 2 + 1][lr];
            size_t r = br + tid;
            if (r < (size_t)R) {
                al_s[r * H + blockIdx.y] = s;
                al_d[r * H + blockIdx.y] = d;
            }
        }
    }

#pragma unroll
    for (int m = 0; m < 4; m++) {
        int r0 = wr + m * 16 + (lane >> 4) * 4;
#pragma unroll
        for (int n = 0; n < 4; n++) {
            int c = (int)bc + wc + n * 16 + (lane & 15);
            float bv = bias ? bias[c] : 0.f;
#pragma unroll
            for (int j = 0; j < 4; j++) {
                size_t r = br + r0 + j;
                if (r < (size_t)R) {
                    float v = acc[m][n][j] + bv;
                    if (Cf) Cf[r * ldc + c] = v;
                    if (C16) C16[r * ldc + c] = f2bf(v);
                }
            }
        }
    }
}

// ---------------------------------------------------------------------------
// Fused GAT aggregation + bias + ELU + LayerNorm + residual.
// Wave-per-row gather: uint4 (8 bf16) per lane per edge.
//   C=512: 4 waves, wave wv handles edges j%4==wv over the full row;
//          partials combined via LDS.  Lane owns channels 8*lane..+7.
//   C=128: 1 wave, 16 lanes per row, 4 edge groups; combined via shfl_xor.
// ---------------------------------------------------------------------------
template <int C, int HEADS, int RES>
__global__ __launch_bounds__(C / 2) void gat_aggregate(
    const unsigned short* __restrict__ xp16, const float* __restrict__ al_s,
    const float* __restrict__ al_d, const int* __restrict__ row_start,
    const int* __restrict__ srcs, const float* __restrict__ bias,
    const float* __restrict__ gamma, const float* __restrict__ beta,
    const float* __restrict__ h_res, float* __restrict__ out,
    unsigned short* __restrict__ out16, unsigned short* __restrict__ out2_16,
    int out2_stride) {
    const int BLK = C / 2;
    const int NW = BLK / 64;
    int n = blockIdx.x;
    int tid = threadIdx.x;
    int lane = tid & 63, wv = tid >> 6;
    __shared__ int off_sh[64];
    __shared__ float w_sh[64 * HEADS];
    __shared__ float m_sh[HEADS], s_sh[HEADS];
    __shared__ float red_sh[2 * NW];
    __shared__ float part[(C == 512) ? 4 * 512 : 1];
    int base = row_start[n];
    int deg = row_start[n + 1] - base;

    float acc[8] = {};

    if (deg <= 64) {
        // ---- single-pass softmax: wave wv owns head wv; lane e owns edge e ----
        float v = -3.4e38f;
        if (lane < deg) {
            int src = srcs[base + lane];
            if (wv == 0) off_sh[lane] = src * (C * 2);
            float t = al_s[src * HEADS + wv] + al_d[n * HEADS + wv];
            v = t > 0.f ? t : 0.2f * t;
        }
        float m = v;
#pragma unroll
        for (int off = 32; off; off >>= 1) m = fmaxf(m, __shfl_xor(m, off));
        float p = expf(v - m);
        float s = p;
#pragma unroll
        for (int off = 32; off; off >>= 1) s += __shfl_xor(s, off);
        s += 1e-16f;
        if (lane < deg) w_sh[lane * HEADS + wv] = p / s;
        __syncthreads();
        // ---- gather ----
        if (C == 512) {
            int head = lane >> 4;
            const char* xb = (const char*)xp16 + lane * 16;
            for (int j = wv; j < deg; j += 4) {
                uint4 vv = *(const uint4*)(xb + off_sh[j]);
                fma8(acc, vv, w_sh[j * HEADS + head]);
            }
        } else {
            int li = lane & 15, rg = lane >> 4;
            const char* xb = (const char*)xp16 + li * 16;
            for (int j = rg; j < deg; j += 4) {
                uint4 vv = *(const uint4*)(xb + off_sh[j]);
                fma8(acc, vv, w_sh[j]);
            }
        }
    } else {
        // ---- generic path (rare): 2-pass stats + on-the-fly weights ----
        for (int hh = wv; hh < HEADS; hh += NW) {
            float ald = al_d[n * HEADS + hh];
            float m = -3.4e38f;
            for (int e = lane; e < deg; e += 64) {
                float v = al_s[srcs[base + e] * HEADS + hh] + ald;
                v = v > 0.f ? v : 0.2f * v;
                m = fmaxf(m, v);
            }
#pragma unroll
            for (int off = 32; off; off >>= 1) m = fmaxf(m, __shfl_xor(m, off));
            float s = 0.f;
            for (int e = lane; e < deg; e += 64) {
                float v = al_s[srcs[base + e] * HEADS + hh] + ald;
                v = v > 0.f ? v : 0.2f * v;
                s += expf(v - m);
            }
#pragma unroll
            for (int off = 32; off; off >>= 1) s += __shfl_xor(s, off);
            if (lane == 0) { m_sh[hh] = m; s_sh[hh] = s + 1e-16f; }
        }
        __syncthreads();
        if (C == 512) {
            int head = lane >> 4;
            float mh = m_sh[head], ssh = s_sh[head];
            float ald = al_d[n * HEADS + head];
            const char* xb = (const char*)xp16 + lane * 16;
            for (int j = wv; j < deg; j += 4) {
                int src = srcs[base + j];
                float t = al_s[src * HEADS + head] + ald;
                t = t > 0.f ? t : 0.2f * t;
                float w = expf(t - mh) / ssh;
                uint4 vv = *(const uint4*)(xb + (size_t)src * (C * 2));
                fma8(acc, vv, w);
            }
        } else {
            int li = lane & 15, rg = lane >> 4;
            float mh = m_sh[0], ssh = s_sh[0];
            float ald = al_d[n];
            const char* xb = (const char*)xp16 + li * 16;
            for (int j = rg; j < deg; j += 4) {
                int src = srcs[base + j];
                float t = al_s[src] + ald;
                t = t > 0.f ? t : 0.2f * t;
                float w = expf(t - mh) / ssh;
                uint4 vv = *(const uint4*)(xb + (size_t)src * (C * 2));
                fma8(acc, vv, w);
            }
        }
    }

    if (C == 512) {
        // ---- combine wave partials via LDS; epilogue on 2 ch/thread ----
        *(f32x4*)&part[wv * 512 + 8 * lane] =
            (f32x4){acc[0], acc[1], acc[2], acc[3]};
        *(f32x4*)&part[wv * 512 + 8 * lane + 4] =
            (f32x4){acc[4], acc[5], acc[6], acc[7]};
        __syncthreads();
        const int c0 = 2 * tid;
        float v0 = 0.f, v1 = 0.f;
#pragma unroll
        for (int w2 = 0; w2 < 4; w2++) {
            float2 pv = *(const float2*)&part[w2 * 512 + c0];
            v0 += pv.x;
            v1 += pv.y;
        }
        float2 bv = *reinterpret_cast<const float2*>(&bias[c0]);
        v0 += bv.x;
        v1 += bv.y;
        v0 = v0 > 0.f ? v0 : expm1f(v0);
        v1 = v1 > 0.f ? v1 : expm1f(v1);
        float s = v0 + v1, q = v0 * v0 + v1 * v1;
#pragma unroll
        for (int off = 32; off; off >>= 1) {
            s += __shfl_xor(s, off);
            q += __shfl_xor(q, off);
        }
        __syncthreads();
        if (lane == 0) { red_sh[wv * 2] = s; red_sh[wv * 2 + 1] = q; }
        __syncthreads();
        s = 0.f;
        q = 0.f;
#pragma unroll
        for (int w2 = 0; w2 < NW; w2++) {
            s += red_sh[w2 * 2];
            q += red_sh[w2 * 2 + 1];
        }
        float mu = s / C;
        float var = q / C - mu * mu;
        float rstd = 1.0f / sqrtf(var + 1e-5f);
        float2 gv = *reinterpret_cast<const float2*>(&gamma[c0]);
        float2 bev = *reinterpret_cast<const float2*>(&beta[c0]);
        v0 = (v0 - mu) * rstd * gv.x + bev.x;
        v1 = (v1 - mu) * rstd * gv.y + bev.y;
        if (RES == 1) {
            float2 rv = *reinterpret_cast<const float2*>(&h_res[(size_t)n * C + c0]);
            v0 += rv.x;
            v1 += rv.y;
        }
        *reinterpret_cast<float2*>(&out[(size_t)n * C + c0]) = make_float2(v0, v1);
        if (out16) {
            ushort2 o = {f2bf(v0), f2bf(v1)};
            *reinterpret_cast<ushort2*>(&out16[(size_t)n * C + c0]) = o;
        }
    } else {
        // ---- C=128: combine 4 edge-groups via shfl; 8 ch/lane epilogue ----
#pragma unroll
        for (int k = 0; k < 8; k++) {
            acc[k] += __shfl_xor(acc[k], 16);
            acc[k] += __shfl_xor(acc[k], 32);
        }
        int li = lane & 15;
        int ch0 = 8 * li;
        float vals[8];
        float4 b0 = *(const float4*)&bias[ch0];
        float4 b1 = *(const float4*)&bias[ch0 + 4];
        vals[0] = acc[0] + b0.x; vals[1] = acc[1] + b0.y;
        vals[2] = acc[2] + b0.z; vals[3] = acc[3] + b0.w;
        vals[4] = acc[4] + b1.x; vals[5] = acc[5] + b1.y;
        vals[6] = acc[6] + b1.z; vals[7] = acc[7] + b1.w;
        float s = 0.f, q = 0.f;
#pragma unroll
        for (int k = 0; k < 8; k++) {
            vals[k] = vals[k] > 0.f ? vals[k] : expm1f(vals[k]);
            s += vals[k];
            q += vals[k] * vals[k];
        }
#pragma unroll
        for (int off = 8; off; off >>= 1) {
            s += __shfl_xor(s, off);
            q += __shfl_xor(q, off);
        }
        float mu = s / C;
        float var = q / C - mu * mu;
        float rstd = 1.0f / sqrtf(var + 1e-5f);
        float4 g0 = *(const float4*)&gamma[ch0];
        float4 g1 = *(const float4*)&gamma[ch0 + 4];
        float4 be0v = *(const float4*)&beta[ch0];
        float4 be1v = *(const float4*)&beta[ch0 + 4];
        float gg[8] = {g0.x, g0.y, g0.z, g0.w, g1.x, g1.y, g1.z, g1.w};
        float bb[8] = {be0v.x, be0v.y, be0v.z, be0v.w, be1v.x, be1v.y, be1v.z, be1v.w};
#pragma unroll
        for (int k = 0; k < 8; k++) vals[k] = (vals[k] - mu) * rstd * gg[k] + bb[k];
        if (RES == 2) {
            const float* r = &h_res[(size_t)n * 512 + 4 * ch0];
#pragma unroll
            for (int k = 0; k < 8; k++) {
                float4 rv = *(const float4*)&r[4 * k];
                vals[k] += 0.25f * (rv.x + rv.y + rv.z + rv.w);
            }
        }
        if (lane < 16) {
            *(float4*)&out[(size_t)n * C + ch0] =
                make_float4(vals[0], vals[1], vals[2], vals[3]);
            *(float4*)&out[(size_t)n * C + ch0 + 4] =
                make_float4(vals[4], vals[5], vals[6], vals[7]);
            uint4 pk;
            pk.x = (unsigned)f2bf(vals[0]) | ((unsigned)f2bf(vals[1]) << 16);
            pk.y = (unsigned)f2bf(vals[2]) | ((unsigned)f2bf(vals[3]) << 16);
            pk.z = (unsigned)f2bf(vals[4]) | ((unsigned)f2bf(vals[5]) << 16);
            pk.w = (unsigned)f2bf(vals[6]) | ((unsigned)f2bf(vals[7]) << 16);
            if (out16) *(uint4*)&out16[(size_t)n * C + ch0] = pk;
            if (out2_16) *(uint4*)&out2_16[(size_t)n * out2_stride + ch0] = pk;
        }
    }
}

// ---------------------------------------------------------------------------
// Temporal self-attention over T=2 states. qkv16:[2N,384] bf16 -> om16 bf16
// ---------------------------------------------------------------------------
__global__ __launch_bounds__(128) void temporal_attn(
    const unsigned short* __restrict__ qkv16, unsigned short* __restrict__ om16) {
    __shared__ float sh[768];
    int n = blockIdx.x;
    int c = threadIdx.x;
    for (int i = c; i < 768; i += 128) {
        int t = i / 384;
        sh[i] = bf2f(qkv16[(size_t)(n * 2 + t) * 384 + (i - t * 384)]);
    }
    __syncthreads();
    int head = c >> 5;
    int hb = head * 32;
    const float scale = 0.17677669529663687f;
    float o[2];
#pragma unroll
    for (int qt = 0; qt < 2; qt++) {
        float s0 = 0.f, s1 = 0.f;
#pragma unroll
        for (int d = 0; d < 32; d++) {
            float qv = sh[qt * 384 + hb + d];
            s0 = fmaf(qv, sh[0 * 384 + 128 + hb + d], s0);
            s1 = fmaf(qv, sh[1 * 384 + 128 + hb + d], s1);
        }
        s0 *= scale; s1 *= scale;
        float m = fmaxf(s0, s1);
        float p0 = expf(s0 - m), p1 = expf(s1 - m);
        float inv = 1.0f / (p0 + p1);
        o[qt] = p0 * inv * sh[0 * 384 + 256 + c] + p1 * inv * sh[1 * 384 + 256 + c];
    }
    om16[(size_t)n * 128 + c] = f2bf(0.5f * (o[0] + o[1]));
}

// ---------------------------------------------------------------------------

extern "C" void kernel_launch(void* const* d_in, const int* in_sizes, int n_in,
                              void* d_out, int out_size, void* d_ws, size_t ws_size,
                              hipStream_t stream) {
    const float* x   = (const float*)d_in[0];
    const int*   ei  = (const int*)d_in[1];
    const float* Wp  = (const float*)d_in[2];
    const float* bp  = (const float*)d_in[3];
    const float* W0  = (const float*)d_in[4];
    const float* as0 = (const float*)d_in[5];
    const float* ad0 = (const float*)d_in[6];
    const float* b0  = (const float*)d_in[7];
    const float* W1  = (const float*)d_in[8];
    const float* as1 = (const float*)d_in[9];
    const float* ad1 = (const float*)d_in[10];
    const float* b1  = (const float*)d_in[11];
    const float* W2  = (const float*)d_in[12];
    const float* as2 = (const float*)d_in[13];
    const float* ad2 = (const float*)d_in[14];
    const float* b2  = (const float*)d_in[15];
    const float* g0  = (const float*)d_in[16];
    const float* be0 = (const float*)d_in[17];
    const float* g1  = (const float*)d_in[18];
    const float* be1 = (const float*)d_in[19];
    const float* g2  = (const float*)d_in[20];
    const float* be2 = (const float*)d_in[21];
    const float* Wqkv = (const float*)d_in[22];
    const float* bqkv = (const float*)d_in[23];
    const float* Wo  = (const float*)d_in[24];
    const float* bo  = (const float*)d_in[25];
    float* out = (float*)d_out;

    const int N = N_NODES;
    float* f = (float*)d_ws;
    const size_t NH = (size_t)N * 512;
    // fp32 buffers (residual/state chain)
    float* hA  = f;                 // [N,512]
    float* hB  = hA + NH;           // [N,512]
    float* als = hB + NH;           // [N,4]
    float* ald = als + (size_t)N * 4;
    // int buffers
    int* row_start  = (int*)(ald + (size_t)N * 4);
    int* cursor     = row_start + (N + 1);
    int* sorted_id  = cursor + N;
    int* sorted_src = sorted_id + ETOT;
    int* bsum       = sorted_src + ETOT;          // NBLK_SCAN
    // bf16 buffers (aligned to 64B for uint4 / global_load_lds dwordx4)
    uintptr_t pa = (uintptr_t)(bsum + NBLK_SCAN + 1);
    pa = (pa + 63) & ~(uintptr_t)63;
    unsigned short* x16   = (unsigned short*)pa;
    unsigned short* h16n  = x16 + (size_t)NPAD * 128;         // [NPAD,128]
    unsigned short* h16w  = h16n + (size_t)NPAD * 128;        // [NPAD,512]
    unsigned short* xp16  = h16w + (size_t)NPAD * 512;        // [NPAD,512]
    unsigned short* st16  = xp16 + (size_t)NPAD * 512;        // [NPAD2,128]
    unsigned short* qkv16 = st16 + (size_t)NPAD2 * 128;       // [NPAD2,384]
    unsigned short* om16  = qkv16 + (size_t)NPAD2 * 384;      // [NPAD,128]
    unsigned short* w16   = om16 + (size_t)NPAD * 128;
    unsigned short* Wp16   = w16;
    unsigned short* W016   = Wp16 + 128 * 128;
    unsigned short* W116   = W016 + 512 * 128;
    unsigned short* W216   = W116 + 512 * 512;
    unsigned short* Wqkv16 = W216 + 128 * 512;
    unsigned short* Wo16   = Wqkv16 + 384 * 128;

    // ---- zero pad rows of GEMM A-operand mirrors ----
    zero_pads<<<192, 256, 0, stream>>>(x16, h16n, h16w, st16, om16);

    // ---- weight conversions ----
    conv_bf16<<<(128 * 128 + 255) / 256, 256, 0, stream>>>(Wp, Wp16, 128 * 128);
    conv_bf16<<<(512 * 128 + 255) / 256, 256, 0, stream>>>(W0, W016, 512 * 128);
    conv_bf16<<<(512 * 512 + 255) / 256, 256, 0, stream>>>(W1, W116, 512 * 512);
    conv_bf16<<<(128 * 512 + 255) / 256, 256, 0, stream>>>(W2, W216, 128 * 512);
    conv_bf16<<<(384 * 128 + 255) / 256, 256, 0, stream>>>(Wqkv, Wqkv16, 384 * 128);
    conv_bf16<<<(128 * 128 + 255) / 256, 256, 0, stream>>>(Wo, Wo16, 128 * 128);
    conv_bf16<<<(N * 128 + 255) / 256, 256, 0, stream>>>(x, x16, N * 128);

    // ---- edge preprocessing (deterministic counting sort by dst) ----
    hipMemsetAsync(cursor, 0, N * sizeof(int), stream);
    hist_kernel<<<1024, 256, 0, stream>>>(ei, cursor);
    scanA<<<NBLK_SCAN, 256, 0, stream>>>(cursor, row_start + 1, bsum);
    scanB<<<1, 64, 0, stream>>>(bsum, row_start);
    scanC<<<NBLK_SCAN, 256, 0, stream>>>(cursor, row_start, bsum);
    scatter_kernel<<<1024, 256, 0, stream>>>(ei, cursor, sorted_id);
    segsort_kernel<<<(N + 255) / 256, 256, 0, stream>>>(ei, row_start, sorted_id,
                                                        sorted_src);

    const int GX = NPAD / 128;  // 157
    // ---- input projection -> h16n ----
    {
        dim3 g(GX, 1);
        gemm_mfma<<<g, 256, 0, stream>>>(x16, Wp16, bp, nullptr, h16n, N, 128, 128,
                                         nullptr, nullptr, nullptr, nullptr, 0);
    }

    float* cur = hA;
    float* nxt = hB;
    for (int t = 0; t < 2; t++) {
        // layer 0: 128 -> 512 (4 heads)
        {
            dim3 g(GX, 4);
            gemm_mfma<<<g, 256, 0, stream>>>(h16n, W016, nullptr, nullptr, xp16,
                                             N, 128, 512, as0, ad0, als, ald, 4);
            gat_aggregate<512, 4, 0><<<N, 256, 0, stream>>>(
                xp16, als, ald, row_start, sorted_src, b0, g0, be0, nullptr, nxt,
                h16w, nullptr, 0);
            float* tmp = cur; cur = nxt; nxt = tmp;
        }
        // layer 1: 512 -> 512 (4 heads), residual
        {
            dim3 g(GX, 4);
            gemm_mfma<<<g, 256, 0, stream>>>(h16w, W116, nullptr, nullptr, xp16,
                                             N, 512, 512, as1, ad1, als, ald, 4);
            gat_aggregate<512, 4, 1><<<N, 256, 0, stream>>>(
                xp16, als, ald, row_start, sorted_src, b1, g1, be1, cur, nxt,
                h16w, nullptr, 0);
            float* tmp = cur; cur = nxt; nxt = tmp;
        }
        // layer 2: 512 -> 128 (1 head), pooled residual
        {
            dim3 g(GX, 1);
            gemm_mfma<<<g, 256, 0, stream>>>(h16w, W216, nullptr, nullptr, xp16,
                                             N, 512, 128, as2, ad2, als, ald, 1);
            gat_aggregate<128, 1, 2><<<N, 64, 0, stream>>>(
                xp16, als, ald, row_start, sorted_src, b2, g2, be2, cur, nxt,
                h16n, st16 + (size_t)t * 128, 256);
            float* tmp = cur; cur = nxt; nxt = tmp;
        }
    }

    // ---- temporal attention ----
    {
        dim3 g(NPAD2 / 128, 3);
        gemm_mfma<<<g, 256, 0, stream>>>(st16, Wqkv16, bqkv, nullptr, qkv16,
                                         2 * N, 128, 384, nullptr, nullptr,
                                         nullptr, nullptr, 0);
    }
    temporal_attn<<<N, 128, 0, stream>>>(qkv16, om16);
    {
        dim3 g(GX, 1);
        gemm_mfma<<<g, 256, 0, stream>>>(om16, Wo16, bo, out, nullptr,
                                         N, 128, 128, nullptr, nullptr,
                                         nullptr, nullptr, 0);
    }
}